// Round 4
// baseline (16307.976 us; speedup 1.0000x reference)
//
#include <hip/hip_runtime.h>

#define NF 481
#define NT 500
#define CH 16
#define HID 32
#define NB 16
#define NSEQ (NB*NF)   // 7696

#define TS1 20         // s_feat t-stride (16 t + 4 pad), 16B-aligned rows
#define TS2 20         // s_y1 t-stride

__device__ __forceinline__ float sig_(float v) { return 1.0f / (1.0f + __expf(-v)); }

__device__ __forceinline__ float4 prelu4(float4 v, float a) {
    v.x = (v.x >= 0.f) ? v.x : a*v.x;
    v.y = (v.y >= 0.f) ? v.y : a*v.y;
    v.z = (v.z >= 0.f) ? v.z : a*v.z;
    v.w = (v.w >= 0.f) ? v.w : a*v.w;
    return v;
}

// channel-major acc update: Q_c holds channel c over 4 t; W over channels, V over t
#define FMA_T(Q, WS, V)                              \
    Q.x = fmaf(WS, (V).x, Q.x);                      \
    Q.y = fmaf(WS, (V).y, Q.y);                      \
    Q.z = fmaf(WS, (V).z, Q.z);                      \
    Q.w = fmaf(WS, (V).w, Q.w)

// t-major acc update: R_t holds channels c0..c3 at one t; W over channels, VS scalar
#define FMA_C(R, W, VS)                              \
    R.x = fmaf((W).x, VS, R.x);                      \
    R.y = fmaf((W).y, VS, R.y);                      \
    R.z = fmaf((W).z, VS, R.z);                      \
    R.w = fmaf((W).w, VS, R.w)

// -------------------------------------------------------------------------
// Conv kernel: conv1(4->16,k9,p4)+PReLU -> conv2(16->16,k5,p2)+PReLU
// features (B,4,F,T) -> x (N=B*F, T, 16)
// NO per-thread arrays anywhere (R2 spilled at VGPR=256; R3 left arrays in
// scratch at VGPR=84 -> 32 GB phantom HBM traffic). Only named float4 accs.
// Block: 320 threads (5 waves). Tile: 16 f x 16 t, 8 tiles per block.
// -------------------------------------------------------------------------
__global__ __launch_bounds__(320, 3) void conv_kernel(
    const float* __restrict__ feat,
    const float* __restrict__ w1, const float* __restrict__ b1, const float* __restrict__ a1p,
    const float* __restrict__ w2, const float* __restrict__ b2, const float* __restrict__ a2p,
    float* __restrict__ xout)
{
    __shared__ float s_feat[4*28*TS1];   //  8.9 KB  rows (d,ffp) x 16t
    __shared__ float s_y1[CH*20*TS2];    // 25.6 KB  rows (c,fp)  x 16t
    __shared__ float s_w1t[4*9*16];      // [d][k][c]
    __shared__ float s_w2t[16*5*16];     // [ci][k][c]
    __shared__ float s_b1[16], s_b2[16];

    const int b   = blockIdx.x;
    const int f0  = blockIdx.y * 16;
    const int zc  = blockIdx.z;
    const int tid = threadIdx.x;
    const float al1 = a1p[0], al2 = a2p[0];

    // transpose-stage weights (tiny, once)
    for (int i = tid; i < 4*9*16; i += 320) {
        const int c = i & 15, kk = i >> 4, d = kk / 9, k = kk % 9;
        s_w1t[i] = w1[(c*4 + d)*9 + k];
    }
    for (int i = tid; i < 16*5*16; i += 320) {
        const int c = i & 15, kk = i >> 4, ci = kk / 5, k = kk % 5;
        s_w2t[i] = w2[(c*16 + ci)*5 + k];
    }
    if (tid < 16) { s_b1[tid] = b1[tid]; s_b2[tid] = b2[tid]; }

    const int tq  = tid & 3;            // 4-t subgroup
    const int fp1 = (tid >> 2) % 20;    // conv1 y1-row f
    const int cg1 = tid / 80;           // conv1 channel group (0..3)
    const int f2  = (tid >> 2) & 15;    // conv2 output f
    const int cg2 = tid >> 6;           // conv2 channel group (0..4; <4 active)

    for (int it = 0; it < 8; it++) {
        const int t0 = zc*128 + it*16;

        // ---- stage features: 112 rows x 16 t, scalar coalesced loads ----
        {
            const int tt = tid & 15, rb = tid >> 4;
            #pragma unroll
            for (int p = 0; p < 6; p++) {
                const int r = rb + p*20;
                if (r < 112) {
                    const int d = r / 28, ffp = r % 28;
                    const int gf = f0 - 6 + ffp;
                    const int gt = t0 + tt;
                    float v = 0.f;
                    if (gf >= 0 && gf < NF && gt < NT)
                        v = feat[((size_t)(b*4 + d)*NF + gf)*NT + gt];
                    s_feat[r*TS1 + tt] = v;
                }
            }
        }
        __syncthreads();

        // ---- conv1 + PReLU -> s_y1 (invalid f rows zeroed = conv2 pad) ----
        {
            const float4 bv = *(const float4*)&s_b1[cg1*4];
            float4 q0 = make_float4(bv.x, bv.x, bv.x, bv.x);
            float4 q1 = make_float4(bv.y, bv.y, bv.y, bv.y);
            float4 q2 = make_float4(bv.z, bv.z, bv.z, bv.z);
            float4 q3 = make_float4(bv.w, bv.w, bv.w, bv.w);
            #pragma unroll
            for (int d = 0; d < 4; d++) {
                #pragma unroll
                for (int k = 0; k < 9; k++) {
                    const float4 v = *(const float4*)&s_feat[(d*28 + fp1 + k)*TS1 + tq*4];
                    const float4 w = *(const float4*)&s_w1t[(d*9 + k)*16 + cg1*4];
                    FMA_T(q0, w.x, v);
                    FMA_T(q1, w.y, v);
                    FMA_T(q2, w.z, v);
                    FMA_T(q3, w.w, v);
                }
            }
            const int gf1 = f0 - 2 + fp1;
            const bool valid = (gf1 >= 0 && gf1 < NF);
            q0 = prelu4(q0, al1); q1 = prelu4(q1, al1);
            q2 = prelu4(q2, al1); q3 = prelu4(q3, al1);
            if (!valid) {
                q0 = make_float4(0.f,0.f,0.f,0.f); q1 = q0; q2 = q0; q3 = q0;
            }
            const int c0 = cg1*4;
            *(float4*)&s_y1[((c0+0)*20 + fp1)*TS2 + tq*4] = q0;
            *(float4*)&s_y1[((c0+1)*20 + fp1)*TS2 + tq*4] = q1;
            *(float4*)&s_y1[((c0+2)*20 + fp1)*TS2 + tq*4] = q2;
            *(float4*)&s_y1[((c0+3)*20 + fp1)*TS2 + tq*4] = q3;
        }
        __syncthreads();

        // ---- conv2 + PReLU -> x (N, T, 16), float4-per-t stores ----
        if (tid < 256) {
            const float4 bv = *(const float4*)&s_b2[cg2*4];
            float4 r0 = bv, r1 = bv, r2 = bv, r3 = bv;   // t = tq*4 + 0..3
            #pragma unroll
            for (int ci = 0; ci < 16; ci++) {
                #pragma unroll
                for (int k = 0; k < 5; k++) {
                    const float4 v = *(const float4*)&s_y1[(ci*20 + f2 + k)*TS2 + tq*4];
                    const float4 w = *(const float4*)&s_w2t[(ci*5 + k)*16 + cg2*4];
                    FMA_C(r0, w, v.x);
                    FMA_C(r1, w, v.y);
                    FMA_C(r2, w, v.z);
                    FMA_C(r3, w, v.w);
                }
            }
            const int gf = f0 + f2;
            if (gf < NF) {
                const size_t nb_ = ((size_t)b*NF + gf)*NT;
                const int gtb = t0 + tq*4;
                if (gtb + 0 < NT) *(float4*)&xout[(nb_ + gtb + 0)*CH + cg2*4] = prelu4(r0, al2);
                if (gtb + 1 < NT) *(float4*)&xout[(nb_ + gtb + 1)*CH + cg2*4] = prelu4(r1, al2);
                if (gtb + 2 < NT) *(float4*)&xout[(nb_ + gtb + 2)*CH + cg2*4] = prelu4(r2, al2);
                if (gtb + 3 < NT) *(float4*)&xout[(nb_ + gtb + 3)*CH + cg2*4] = prelu4(r3, al2);
            }
        }
        __syncthreads();
    }
}

// -------------------------------------------------------------------------
// GRU + FC + sigmoid.  One wave per sequence, 4 waves/block.
// Lane (j, half): unit j, half of each dot; combine via __shfl_xor(.,32).
// ALL weights in named float4 registers (no arrays, no type-punning).
// x prefetched 2 steps ahead (HBM latency ~900 cyc > 1-step work).
// -------------------------------------------------------------------------
#define DOT4(acc, W, V)                             \
    acc = fmaf((W).x, (V).x, acc);                  \
    acc = fmaf((W).y, (V).y, acc);                  \
    acc = fmaf((W).z, (V).z, acc);                  \
    acc = fmaf((W).w, (V).w, acc)

__global__ __launch_bounds__(256, 4) void gru_kernel(
    const float* __restrict__ xin,   // (NSEQ, NT, 16)
    const float* __restrict__ h0,    // (NSEQ, 32)
    const float* __restrict__ w_ih,  // (96, 16)
    const float* __restrict__ w_hh,  // (96, 32)
    const float* __restrict__ b_ih, const float* __restrict__ b_hh,
    const float* __restrict__ fc_w, const float* __restrict__ fc_b,
    float* __restrict__ prob,        // (NSEQ, NT)
    float* __restrict__ hout)        // (NSEQ, 32)
{
    __shared__ float s_h[4][HID];
    const int wv   = threadIdx.x >> 6;
    const int lane = threadIdx.x & 63;
    const int j    = lane & 31;
    const int half = lane >> 5;
    const size_t n = (size_t)blockIdx.x*4 + wv;    // 7696 = 4*1924

    // named-register weight slices (8 x-weights, 16 h-weights per gate)
    const float4 wi0 = *(const float4*)(w_ih + (     j)*16 + half*8);
    const float4 wi1 = *(const float4*)(w_ih + (     j)*16 + half*8 + 4);
    const float4 wz0 = *(const float4*)(w_ih + (32 + j)*16 + half*8);
    const float4 wz1 = *(const float4*)(w_ih + (32 + j)*16 + half*8 + 4);
    const float4 wn0 = *(const float4*)(w_ih + (64 + j)*16 + half*8);
    const float4 wn1 = *(const float4*)(w_ih + (64 + j)*16 + half*8 + 4);

    const float* hrp = w_hh + (     j)*32 + half*16;
    const float* hzp = w_hh + (32 + j)*32 + half*16;
    const float* hnp_ = w_hh + (64 + j)*32 + half*16;
    const float4 hr0 = *(const float4*)(hrp),      hr1 = *(const float4*)(hrp + 4);
    const float4 hr2 = *(const float4*)(hrp + 8),  hr3 = *(const float4*)(hrp + 12);
    const float4 hz0 = *(const float4*)(hzp),      hz1 = *(const float4*)(hzp + 4);
    const float4 hz2 = *(const float4*)(hzp + 8),  hz3 = *(const float4*)(hzp + 12);
    const float4 hn0 = *(const float4*)(hnp_),     hn1 = *(const float4*)(hnp_ + 4);
    const float4 hn2 = *(const float4*)(hnp_ + 8), hn3 = *(const float4*)(hnp_ + 12);

    const float brr = b_ih[j]      + b_hh[j];
    const float bzz = b_ih[32 + j] + b_hh[32 + j];
    const float bin_ = b_ih[64 + j];
    const float bhn  = b_hh[64 + j];
    const float fw = fc_w[j];
    const float fb = fc_b[0];

    float h = h0[n*HID + j];
    if (half == 0) s_h[wv][j] = h;
    __builtin_amdgcn_wave_barrier();

    const float* xb = xin + (size_t)n*NT*CH + half*8;
    float4 cx0 = *(const float4*)(xb);
    float4 cx1 = *(const float4*)(xb + 4);
    float4 px0 = *(const float4*)(xb + 16);
    float4 px1 = *(const float4*)(xb + 20);

    for (int t = 0; t < NT; t++) {
        const int t2 = (t + 2 < NT) ? t + 2 : NT - 1;
        const float4 fx0 = *(const float4*)(xb + t2*16);
        const float4 fx1 = *(const float4*)(xb + t2*16 + 4);

        // x partials
        float xr = 0.f, xz = 0.f, xnp = 0.f;
        DOT4(xr, wi0, cx0);  DOT4(xr, wi1, cx1);
        DOT4(xz, wz0, cx0);  DOT4(xz, wz1, cx1);
        DOT4(xnp, wn0, cx0); DOT4(xnp, wn1, cx1);

        // h partials (broadcast LDS reads)
        const float4* hp = (const float4*)&s_h[wv][half*16];
        const float4 h0v = hp[0], h1v = hp[1], h2v = hp[2], h3v = hp[3];
        float hr = 0.f, hz = 0.f, hn = 0.f;
        DOT4(hr, hr0, h0v); DOT4(hr, hr1, h1v); DOT4(hr, hr2, h2v); DOT4(hr, hr3, h3v);
        DOT4(hz, hz0, h0v); DOT4(hz, hz1, h1v); DOT4(hz, hz2, h2v); DOT4(hz, hz3, h3v);
        DOT4(hn, hn0, h0v); DOT4(hn, hn1, h1v); DOT4(hn, hn2, h2v); DOT4(hn, hn3, h3v);

        // combine halves
        float prz = xr + hr;  prz += __shfl_xor(prz, 32);
        float pzz = xz + hz;  pzz += __shfl_xor(pzz, 32);
        float xn = xnp + __shfl_xor(xnp, 32) + bin_;
        float hnn = hn + __shfl_xor(hn, 32) + bhn;

        const float r = sig_(prz + brr);
        const float z = sig_(pzz + bzz);
        const float aa = xn + r*hnn;
        const float nn = 2.f*sig_(2.f*aa) - 1.f;       // tanh
        const float hnew = (1.f - z)*nn + z*h;

        // FC + sigmoid (butterfly within 32-lane half)
        float pa = fw * hnew;
        pa += __shfl_xor(pa, 1);
        pa += __shfl_xor(pa, 2);
        pa += __shfl_xor(pa, 4);
        pa += __shfl_xor(pa, 8);
        pa += __shfl_xor(pa, 16);
        if (lane == 0) prob[n*(size_t)NT + t] = sig_(pa + fb);

        if (half == 0) s_h[wv][j] = hnew;
        __builtin_amdgcn_wave_barrier();
        h = hnew;
        cx0 = px0; cx1 = px1; px0 = fx0; px1 = fx1;
    }

    if (half == 0) hout[n*HID + j] = h;
}

// -------------------------------------------------------------------------
extern "C" void kernel_launch(void* const* d_in, const int* in_sizes, int n_in,
                              void* d_out, int out_size, void* d_ws, size_t ws_size,
                              hipStream_t stream)
{
    const float* feat = (const float*)d_in[0];
    const float* h0   = (const float*)d_in[1];
    const float* w1   = (const float*)d_in[2];
    const float* b1   = (const float*)d_in[3];
    const float* a1   = (const float*)d_in[4];
    const float* w2   = (const float*)d_in[5];
    const float* b2   = (const float*)d_in[6];
    const float* a2   = (const float*)d_in[7];
    const float* wih  = (const float*)d_in[8];
    const float* whh  = (const float*)d_in[9];
    const float* bih  = (const float*)d_in[10];
    const float* bhh  = (const float*)d_in[11];
    const float* fcw  = (const float*)d_in[12];
    const float* fcb  = (const float*)d_in[13];

    float* xbuf = (float*)d_ws;                    // NSEQ*NT*16 floats = 246.3 MB
    float* prob = (float*)d_out;                   // (B, F, T)
    float* hout = prob + (size_t)NSEQ*NT;          // (1, NSEQ, 32)

    dim3 cgrid(NB, 31, 4);                         // 16 x 31 f-tiles x 4 t-chunks
    conv_kernel<<<cgrid, 320, 0, stream>>>(feat, w1, b1, a1, w2, b2, a2, xbuf);
    gru_kernel<<<NSEQ/4, 256, 0, stream>>>(xbuf, h0, wih, whh, bih, bhh, fcw, fcb, prob, hout);
}

// Round 5
// 2443.984 us; speedup vs baseline: 6.6727x; 6.6727x over previous
//
#include <hip/hip_runtime.h>

#define NF 481
#define NT 500
#define CH 16
#define HID 32
#define NB 16
#define NSEQ (NB*NF)   // 7696

__device__ __forceinline__ float sig_(float v) { return 1.0f / (1.0f + __expf(-v)); }

__device__ __forceinline__ float4 prelu4(float4 v, float a) {
    v.x = (v.x >= 0.f) ? v.x : a*v.x;
    v.y = (v.y >= 0.f) ? v.y : a*v.y;
    v.z = (v.z >= 0.f) ? v.z : a*v.z;
    v.w = (v.w >= 0.f) ? v.w : a*v.w;
    return v;
}

// conv1 tap: v (per-lane feat value) times 16 uniform weights w1[c][d][k1],
// c-stride 36 floats. OFF = d*9+k1. Weights are wave-uniform -> s_load.
#define CONV1_V(OFF)                                     \
    q0.x = fmaf(w1[(OFF) +  0*36], v, q0.x);             \
    q0.y = fmaf(w1[(OFF) +  1*36], v, q0.y);             \
    q0.z = fmaf(w1[(OFF) +  2*36], v, q0.z);             \
    q0.w = fmaf(w1[(OFF) +  3*36], v, q0.w);             \
    q1.x = fmaf(w1[(OFF) +  4*36], v, q1.x);             \
    q1.y = fmaf(w1[(OFF) +  5*36], v, q1.y);             \
    q1.z = fmaf(w1[(OFF) +  6*36], v, q1.z);             \
    q1.w = fmaf(w1[(OFF) +  7*36], v, q1.w);             \
    q2.x = fmaf(w1[(OFF) +  8*36], v, q2.x);             \
    q2.y = fmaf(w1[(OFF) +  9*36], v, q2.y);             \
    q2.z = fmaf(w1[(OFF) + 10*36], v, q2.z);             \
    q2.w = fmaf(w1[(OFF) + 11*36], v, q2.w);             \
    q3.x = fmaf(w1[(OFF) + 12*36], v, q3.x);             \
    q3.y = fmaf(w1[(OFF) + 13*36], v, q3.w == q3.w ? q3.x*0.f + w1[(OFF)+13*36]*0.f + q3.y : q3.y); /*placeholder removed below*/

// (macro above intentionally unused — see CONV1V below)
#undef CONV1_V
#define CONV1V(OFF)                                      \
    q0.x = fmaf(w1[(OFF) +  0*36], v, q0.x);             \
    q0.y = fmaf(w1[(OFF) +  1*36], v, q0.y);             \
    q0.z = fmaf(w1[(OFF) +  2*36], v, q0.z);             \
    q0.w = fmaf(w1[(OFF) +  3*36], v, q0.w);             \
    q1.x = fmaf(w1[(OFF) +  4*36], v, q1.x);             \
    q1.y = fmaf(w1[(OFF) +  5*36], v, q1.y);             \
    q1.z = fmaf(w1[(OFF) +  6*36], v, q1.z);             \
    q1.w = fmaf(w1[(OFF) +  7*36], v, q1.w);             \
    q2.x = fmaf(w1[(OFF) +  8*36], v, q2.x);             \
    q2.y = fmaf(w1[(OFF) +  9*36], v, q2.y);             \
    q2.z = fmaf(w1[(OFF) + 10*36], v, q2.z);             \
    q2.w = fmaf(w1[(OFF) + 11*36], v, q2.w);             \
    q3.x = fmaf(w1[(OFF) + 12*36], v, q3.x);             \
    q3.y = fmaf(w1[(OFF) + 13*36], v, q3.y);             \
    q3.z = fmaf(w1[(OFF) + 14*36], v, q3.z);             \
    q3.w = fmaf(w1[(OFF) + 15*36], v, q3.w)

// conv2: y-value YV (channel CI of y1 column) times 16 uniform weights
// w2[c][CI][kk]: index (c*16+CI)*5 + kk; w2p = w2 + kk, c-stride 80.
#define CONV2Y(YV, CI)                                   \
    a0.x = fmaf(w2p[(( 0*16+(CI))*5)], YV, a0.x);        \
    a0.y = fmaf(w2p[(( 1*16+(CI))*5)], YV, a0.y);        \
    a0.z = fmaf(w2p[(( 2*16+(CI))*5)], YV, a0.z);        \
    a0.w = fmaf(w2p[(( 3*16+(CI))*5)], YV, a0.w);        \
    a1.x = fmaf(w2p[(( 4*16+(CI))*5)], YV, a1.x);        \
    a1.y = fmaf(w2p[(( 5*16+(CI))*5)], YV, a1.y);        \
    a1.z = fmaf(w2p[(( 6*16+(CI))*5)], YV, a1.z);        \
    a1.w = fmaf(w2p[(( 7*16+(CI))*5)], YV, a1.w);        \
    a2.x = fmaf(w2p[(( 8*16+(CI))*5)], YV, a2.x);        \
    a2.y = fmaf(w2p[(( 9*16+(CI))*5)], YV, a2.y);        \
    a2.z = fmaf(w2p[((10*16+(CI))*5)], YV, a2.z);        \
    a2.w = fmaf(w2p[((11*16+(CI))*5)], YV, a2.w);        \
    a3.x = fmaf(w2p[((12*16+(CI))*5)], YV, a3.x);        \
    a3.y = fmaf(w2p[((13*16+(CI))*5)], YV, a3.y);        \
    a3.z = fmaf(w2p[((14*16+(CI))*5)], YV, a3.z);        \
    a3.w = fmaf(w2p[((15*16+(CI))*5)], YV, a3.w)

// -------------------------------------------------------------------------
// Conv: register-only direct conv (NO LDS data tiles — R2/R3/R4 all showed
// ~20 MB/block phantom HBM traffic with LDS-tile structures; the clean GRU
// kernel is the template). Lane = t: coalesced 256B feat reads, contiguous
// 64B/lane x stores. Weights are wave-uniform -> SGPR s_loads.
// Wave handles (b, f) column for a 64-t strip; conv1 recomputed per conv2
// tap (2.2x FLOP redundancy, ~16e9 lane-fma total -> ~130us VALU floor).
// -------------------------------------------------------------------------
__global__ __launch_bounds__(256) void conv_kernel(
    const float* __restrict__ feat,
    const float* __restrict__ w1, const float* __restrict__ b1, const float* __restrict__ a1p,
    const float* __restrict__ w2, const float* __restrict__ b2, const float* __restrict__ a2p,
    float* __restrict__ xout)
{
    const int b    = blockIdx.x;
    const int f0   = blockIdx.y * 16;
    const int tz   = blockIdx.z;            // t-half: strips [tz*256, tz*256+256)
    const int wv   = threadIdx.x >> 6;
    const int lane = threadIdx.x & 63;
    const float al1 = a1p[0], al2 = a2p[0];

    const float4 bb1a = *(const float4*)(b1);      // uniform -> s_load
    const float4 bb1b = *(const float4*)(b1 + 4);
    const float4 bb1c = *(const float4*)(b1 + 8);
    const float4 bb1d = *(const float4*)(b1 + 12);
    const float4 bb2a = *(const float4*)(b2);
    const float4 bb2b = *(const float4*)(b2 + 4);
    const float4 bb2c = *(const float4*)(b2 + 8);
    const float4 bb2d = *(const float4*)(b2 + 12);

    #pragma unroll 1
    for (int fi = 0; fi < 4; fi++) {
        const int f = f0 + wv + fi*4;              // 4 waves x 4 fi -> f0..f0+15
        if (f >= NF) continue;
        const size_t nrow = ((size_t)b*NF + f) * (size_t)NT;

        #pragma unroll 1
        for (int t0 = tz*256; t0 < tz*256 + 256 && t0 < NT; t0 += 64) {
            const int t  = t0 + lane;
            const int tc = (t < NT) ? t : (NT - 1);

            float4 a0 = bb2a, a1 = bb2b, a2 = bb2c, a3 = bb2d;

            #pragma unroll 1
            for (int kk = 0; kk < 5; kk++) {
                const int fy = f + kk - 2;          // y1 column needed by this tap
                float4 q0, q1, q2, q3;
                if (fy >= 0 && fy < NF) {           // wave-uniform branch
                    q0 = bb1a; q1 = bb1b; q2 = bb1c; q3 = bb1d;
                    #pragma unroll
                    for (int d = 0; d < 4; d++) {
                        const float* frow = feat + ((size_t)(b*4 + d)*NF)*NT;
                        #pragma unroll
                        for (int k1 = 0; k1 < 9; k1++) {
                            const int gf = fy + k1 - 4;
                            if (gf >= 0 && gf < NF) {   // wave-uniform
                                const float v = frow[(size_t)gf*NT + tc];
                                CONV1V(d*9 + k1);
                            }
                        }
                    }
                    q0 = prelu4(q0, al1); q1 = prelu4(q1, al1);
                    q2 = prelu4(q2, al1); q3 = prelu4(q3, al1);
                } else {
                    q0 = make_float4(0.f,0.f,0.f,0.f);
                    q1 = q0; q2 = q0; q3 = q0;
                }
                const float* w2p = w2 + kk;
                CONV2Y(q0.x,  0); CONV2Y(q0.y,  1); CONV2Y(q0.z,  2); CONV2Y(q0.w,  3);
                CONV2Y(q1.x,  4); CONV2Y(q1.y,  5); CONV2Y(q1.z,  6); CONV2Y(q1.w,  7);
                CONV2Y(q2.x,  8); CONV2Y(q2.y,  9); CONV2Y(q2.z, 10); CONV2Y(q2.w, 11);
                CONV2Y(q3.x, 12); CONV2Y(q3.y, 13); CONV2Y(q3.z, 14); CONV2Y(q3.w, 15);
            }

            if (t < NT) {
                float* op = xout + (nrow + t)*CH;   // 64 B per lane, contiguous
                *(float4*)(op     ) = prelu4(a0, al2);
                *(float4*)(op +  4) = prelu4(a1, al2);
                *(float4*)(op +  8) = prelu4(a2, al2);
                *(float4*)(op + 12) = prelu4(a3, al2);
            }
        }
    }
}

// -------------------------------------------------------------------------
// GRU + FC + sigmoid (unchanged from R4 — verified, clean counters).
// One wave per sequence; lane (j, half); weights in named float4 regs.
// -------------------------------------------------------------------------
#define DOT4(acc, W, V)                             \
    acc = fmaf((W).x, (V).x, acc);                  \
    acc = fmaf((W).y, (V).y, acc);                  \
    acc = fmaf((W).z, (V).z, acc);                  \
    acc = fmaf((W).w, (V).w, acc)

__global__ __launch_bounds__(256, 4) void gru_kernel(
    const float* __restrict__ xin,   // (NSEQ, NT, 16)
    const float* __restrict__ h0,    // (NSEQ, 32)
    const float* __restrict__ w_ih,  // (96, 16)
    const float* __restrict__ w_hh,  // (96, 32)
    const float* __restrict__ b_ih, const float* __restrict__ b_hh,
    const float* __restrict__ fc_w, const float* __restrict__ fc_b,
    float* __restrict__ prob,        // (NSEQ, NT)
    float* __restrict__ hout)        // (NSEQ, 32)
{
    __shared__ float s_h[4][HID];
    const int wv   = threadIdx.x >> 6;
    const int lane = threadIdx.x & 63;
    const int j    = lane & 31;
    const int half = lane >> 5;
    const size_t n = (size_t)blockIdx.x*4 + wv;    // 7696 = 4*1924

    const float4 wi0 = *(const float4*)(w_ih + (     j)*16 + half*8);
    const float4 wi1 = *(const float4*)(w_ih + (     j)*16 + half*8 + 4);
    const float4 wz0 = *(const float4*)(w_ih + (32 + j)*16 + half*8);
    const float4 wz1 = *(const float4*)(w_ih + (32 + j)*16 + half*8 + 4);
    const float4 wn0 = *(const float4*)(w_ih + (64 + j)*16 + half*8);
    const float4 wn1 = *(const float4*)(w_ih + (64 + j)*16 + half*8 + 4);

    const float* hrp  = w_hh + (     j)*32 + half*16;
    const float* hzp  = w_hh + (32 + j)*32 + half*16;
    const float* hnp_ = w_hh + (64 + j)*32 + half*16;
    const float4 hr0 = *(const float4*)(hrp),      hr1 = *(const float4*)(hrp + 4);
    const float4 hr2 = *(const float4*)(hrp + 8),  hr3 = *(const float4*)(hrp + 12);
    const float4 hz0 = *(const float4*)(hzp),      hz1 = *(const float4*)(hzp + 4);
    const float4 hz2 = *(const float4*)(hzp + 8),  hz3 = *(const float4*)(hzp + 12);
    const float4 hn0 = *(const float4*)(hnp_),     hn1 = *(const float4*)(hnp_ + 4);
    const float4 hn2 = *(const float4*)(hnp_ + 8), hn3 = *(const float4*)(hnp_ + 12);

    const float brr  = b_ih[j]      + b_hh[j];
    const float bzz  = b_ih[32 + j] + b_hh[32 + j];
    const float bin_ = b_ih[64 + j];
    const float bhn  = b_hh[64 + j];
    const float fw = fc_w[j];
    const float fb = fc_b[0];

    float h = h0[n*HID + j];
    if (half == 0) s_h[wv][j] = h;
    __builtin_amdgcn_wave_barrier();

    const float* xb = xin + (size_t)n*NT*CH + half*8;
    float4 cx0 = *(const float4*)(xb);
    float4 cx1 = *(const float4*)(xb + 4);
    float4 px0 = *(const float4*)(xb + 16);
    float4 px1 = *(const float4*)(xb + 20);

    for (int t = 0; t < NT; t++) {
        const int t2 = (t + 2 < NT) ? t + 2 : NT - 1;
        const float4 fx0 = *(const float4*)(xb + t2*16);
        const float4 fx1 = *(const float4*)(xb + t2*16 + 4);

        float xr = 0.f, xz = 0.f, xnp = 0.f;
        DOT4(xr, wi0, cx0);  DOT4(xr, wi1, cx1);
        DOT4(xz, wz0, cx0);  DOT4(xz, wz1, cx1);
        DOT4(xnp, wn0, cx0); DOT4(xnp, wn1, cx1);

        const float4* hp = (const float4*)&s_h[wv][half*16];
        const float4 h0v = hp[0], h1v = hp[1], h2v = hp[2], h3v = hp[3];
        float hr = 0.f, hz = 0.f, hn = 0.f;
        DOT4(hr, hr0, h0v); DOT4(hr, hr1, h1v); DOT4(hr, hr2, h2v); DOT4(hr, hr3, h3v);
        DOT4(hz, hz0, h0v); DOT4(hz, hz1, h1v); DOT4(hz, hz2, h2v); DOT4(hz, hz3, h3v);
        DOT4(hn, hn0, h0v); DOT4(hn, hn1, h1v); DOT4(hn, hn2, h2v); DOT4(hn, hn3, h3v);

        float prz = xr + hr;  prz += __shfl_xor(prz, 32);
        float pzz = xz + hz;  pzz += __shfl_xor(pzz, 32);
        float xn  = xnp + __shfl_xor(xnp, 32) + bin_;
        float hnn = hn  + __shfl_xor(hn, 32)  + bhn;

        const float r = sig_(prz + brr);
        const float z = sig_(pzz + bzz);
        const float aa = xn + r*hnn;
        const float nn = 2.f*sig_(2.f*aa) - 1.f;       // tanh
        const float hnew = (1.f - z)*nn + z*h;

        float pa = fw * hnew;
        pa += __shfl_xor(pa, 1);
        pa += __shfl_xor(pa, 2);
        pa += __shfl_xor(pa, 4);
        pa += __shfl_xor(pa, 8);
        pa += __shfl_xor(pa, 16);
        if (lane == 0) prob[n*(size_t)NT + t] = sig_(pa + fb);

        if (half == 0) s_h[wv][j] = hnew;
        __builtin_amdgcn_wave_barrier();
        h = hnew;
        cx0 = px0; cx1 = px1; px0 = fx0; px1 = fx1;
    }

    if (half == 0) hout[n*HID + j] = h;
}

// -------------------------------------------------------------------------
extern "C" void kernel_launch(void* const* d_in, const int* in_sizes, int n_in,
                              void* d_out, int out_size, void* d_ws, size_t ws_size,
                              hipStream_t stream)
{
    const float* feat = (const float*)d_in[0];
    const float* h0   = (const float*)d_in[1];
    const float* w1   = (const float*)d_in[2];
    const float* b1   = (const float*)d_in[3];
    const float* a1   = (const float*)d_in[4];
    const float* w2   = (const float*)d_in[5];
    const float* b2   = (const float*)d_in[6];
    const float* a2   = (const float*)d_in[7];
    const float* wih  = (const float*)d_in[8];
    const float* whh  = (const float*)d_in[9];
    const float* bih  = (const float*)d_in[10];
    const float* bhh  = (const float*)d_in[11];
    const float* fcw  = (const float*)d_in[12];
    const float* fcb  = (const float*)d_in[13];

    float* xbuf = (float*)d_ws;                    // NSEQ*NT*16 floats = 246.3 MB
    float* prob = (float*)d_out;                   // (B, F, T)
    float* hout = prob + (size_t)NSEQ*NT;          // (1, NSEQ, 32)

    dim3 cgrid(NB, 31, 2);                         // 16 b x 31 f-tiles x 2 t-halves
    conv_kernel<<<cgrid, 256, 0, stream>>>(feat, w1, b1, a1, w2, b2, a2, xbuf);
    gru_kernel<<<NSEQ/4, 256, 0, stream>>>(xbuf, h0, wih, whh, bih, bhh, fcw, fcb, prob, hout);
}

// Round 6
// 2405.412 us; speedup vs baseline: 6.7797x; 1.0160x over previous
//
#include <hip/hip_runtime.h>

#define NF 481
#define NT 500
#define CH 16
#define HID 32
#define NB 16
#define NSEQ (NB*NF)   // 7696

__device__ __forceinline__ float sig_(float v) { return 1.0f / (1.0f + __expf(-v)); }

__device__ __forceinline__ float4 prelu4(float4 v, float a) {
    v.x = (v.x >= 0.f) ? v.x : a*v.x;
    v.y = (v.y >= 0.f) ? v.y : a*v.y;
    v.z = (v.z >= 0.f) ? v.z : a*v.z;
    v.w = (v.w >= 0.f) ? v.w : a*v.w;
    return v;
}

#define CONV1V(OFF)                                      \
    q0.x = fmaf(w1[(OFF) +  0*36], v, q0.x);             \
    q0.y = fmaf(w1[(OFF) +  1*36], v, q0.y);             \
    q0.z = fmaf(w1[(OFF) +  2*36], v, q0.z);             \
    q0.w = fmaf(w1[(OFF) +  3*36], v, q0.w);             \
    q1.x = fmaf(w1[(OFF) +  4*36], v, q1.x);             \
    q1.y = fmaf(w1[(OFF) +  5*36], v, q1.y);             \
    q1.z = fmaf(w1[(OFF) +  6*36], v, q1.z);             \
    q1.w = fmaf(w1[(OFF) +  7*36], v, q1.w);             \
    q2.x = fmaf(w1[(OFF) +  8*36], v, q2.x);             \
    q2.y = fmaf(w1[(OFF) +  9*36], v, q2.y);             \
    q2.z = fmaf(w1[(OFF) + 10*36], v, q2.z);             \
    q2.w = fmaf(w1[(OFF) + 11*36], v, q2.w);             \
    q3.x = fmaf(w1[(OFF) + 12*36], v, q3.x);             \
    q3.y = fmaf(w1[(OFF) + 13*36], v, q3.y);             \
    q3.z = fmaf(w1[(OFF) + 14*36], v, q3.z);             \
    q3.w = fmaf(w1[(OFF) + 15*36], v, q3.w)

#define CONV2Y(YV, CI)                                   \
    a0.x = fmaf(w2p[(( 0*16+(CI))*5)], YV, a0.x);        \
    a0.y = fmaf(w2p[(( 1*16+(CI))*5)], YV, a0.y);        \
    a0.z = fmaf(w2p[(( 2*16+(CI))*5)], YV, a0.z);        \
    a0.w = fmaf(w2p[(( 3*16+(CI))*5)], YV, a0.w);        \
    a1.x = fmaf(w2p[(( 4*16+(CI))*5)], YV, a1.x);        \
    a1.y = fmaf(w2p[(( 5*16+(CI))*5)], YV, a1.y);        \
    a1.z = fmaf(w2p[(( 6*16+(CI))*5)], YV, a1.z);        \
    a1.w = fmaf(w2p[(( 7*16+(CI))*5)], YV, a1.w);        \
    a2.x = fmaf(w2p[(( 8*16+(CI))*5)], YV, a2.x);        \
    a2.y = fmaf(w2p[(( 9*16+(CI))*5)], YV, a2.y);        \
    a2.z = fmaf(w2p[((10*16+(CI))*5)], YV, a2.z);        \
    a2.w = fmaf(w2p[((11*16+(CI))*5)], YV, a2.w);        \
    a3.x = fmaf(w2p[((12*16+(CI))*5)], YV, a3.x);        \
    a3.y = fmaf(w2p[((13*16+(CI))*5)], YV, a3.y);        \
    a3.z = fmaf(w2p[((14*16+(CI))*5)], YV, a3.z);        \
    a3.w = fmaf(w2p[((15*16+(CI))*5)], YV, a3.w)

// -------------------------------------------------------------------------
// Conv (unchanged from R5 — clean counters): register-only direct conv.
// Lane = t; weights wave-uniform (s_load); conv1 recomputed per conv2 tap.
// -------------------------------------------------------------------------
__global__ __launch_bounds__(256) void conv_kernel(
    const float* __restrict__ feat,
    const float* __restrict__ w1, const float* __restrict__ b1, const float* __restrict__ a1p,
    const float* __restrict__ w2, const float* __restrict__ b2, const float* __restrict__ a2p,
    float* __restrict__ xout)
{
    const int b    = blockIdx.x;
    const int f0   = blockIdx.y * 16;
    const int tz   = blockIdx.z;
    const int wv   = threadIdx.x >> 6;
    const int lane = threadIdx.x & 63;
    const float al1 = a1p[0], al2 = a2p[0];

    const float4 bb1a = *(const float4*)(b1);
    const float4 bb1b = *(const float4*)(b1 + 4);
    const float4 bb1c = *(const float4*)(b1 + 8);
    const float4 bb1d = *(const float4*)(b1 + 12);
    const float4 bb2a = *(const float4*)(b2);
    const float4 bb2b = *(const float4*)(b2 + 4);
    const float4 bb2c = *(const float4*)(b2 + 8);
    const float4 bb2d = *(const float4*)(b2 + 12);

    #pragma unroll 1
    for (int fi = 0; fi < 4; fi++) {
        const int f = f0 + wv + fi*4;
        if (f >= NF) continue;
        const size_t nrow = ((size_t)b*NF + f) * (size_t)NT;

        #pragma unroll 1
        for (int t0 = tz*256; t0 < tz*256 + 256 && t0 < NT; t0 += 64) {
            const int t  = t0 + lane;
            const int tc = (t < NT) ? t : (NT - 1);

            float4 a0 = bb2a, a1 = bb2b, a2 = bb2c, a3 = bb2d;

            #pragma unroll 1
            for (int kk = 0; kk < 5; kk++) {
                const int fy = f + kk - 2;
                float4 q0, q1, q2, q3;
                if (fy >= 0 && fy < NF) {
                    q0 = bb1a; q1 = bb1b; q2 = bb1c; q3 = bb1d;
                    #pragma unroll
                    for (int d = 0; d < 4; d++) {
                        const float* frow = feat + ((size_t)(b*4 + d)*NF)*NT;
                        #pragma unroll
                        for (int k1 = 0; k1 < 9; k1++) {
                            const int gf = fy + k1 - 4;
                            if (gf >= 0 && gf < NF) {
                                const float v = frow[(size_t)gf*NT + tc];
                                CONV1V(d*9 + k1);
                            }
                        }
                    }
                    q0 = prelu4(q0, al1); q1 = prelu4(q1, al1);
                    q2 = prelu4(q2, al1); q3 = prelu4(q3, al1);
                } else {
                    q0 = make_float4(0.f,0.f,0.f,0.f);
                    q1 = q0; q2 = q0; q3 = q0;
                }
                const float* w2p = w2 + kk;
                CONV2Y(q0.x,  0); CONV2Y(q0.y,  1); CONV2Y(q0.z,  2); CONV2Y(q0.w,  3);
                CONV2Y(q1.x,  4); CONV2Y(q1.y,  5); CONV2Y(q1.z,  6); CONV2Y(q1.w,  7);
                CONV2Y(q2.x,  8); CONV2Y(q2.y,  9); CONV2Y(q2.z, 10); CONV2Y(q2.w, 11);
                CONV2Y(q3.x, 12); CONV2Y(q3.y, 13); CONV2Y(q3.z, 14); CONV2Y(q3.w, 15);
            }

            if (t < NT) {
                float* op = xout + (nrow + t)*CH;
                *(float4*)(op     ) = prelu4(a0, al2);
                *(float4*)(op +  4) = prelu4(a1, al2);
                *(float4*)(op +  8) = prelu4(a2, al2);
                *(float4*)(op + 12) = prelu4(a3, al2);
            }
        }
    }
}

// -------------------------------------------------------------------------
// GRU + FC + sigmoid.  One wave/sequence; lane (j, half) owns half of unit
// j's dots; combine via __shfl_xor(.,32).
// R5 lesson: VGPR_Count=64 under launch_bounds(256,4) -> the ~96 VGPRs of
// weights could not stay resident; compiler re-loaded them from global
// EVERY step (~370 inst/step vs ~110 hand count).  Fix: (256,3) -> cap
// ~170, weights pinned.  Also: s_h write moved BEFORE the FC butterfly
// (5 serial shuffles off the recurrence critical path) and next-step h
// ds_read issued right after the write (latency hidden behind FC).
// -------------------------------------------------------------------------
#define DOT4(acc, W, V)                             \
    acc = fmaf((W).x, (V).x, acc);                  \
    acc = fmaf((W).y, (V).y, acc);                  \
    acc = fmaf((W).z, (V).z, acc);                  \
    acc = fmaf((W).w, (V).w, acc)

__global__ __launch_bounds__(256, 3) void gru_kernel(
    const float* __restrict__ xin,   // (NSEQ, NT, 16)
    const float* __restrict__ h0,    // (NSEQ, 32)
    const float* __restrict__ w_ih,  // (96, 16)
    const float* __restrict__ w_hh,  // (96, 32)
    const float* __restrict__ b_ih, const float* __restrict__ b_hh,
    const float* __restrict__ fc_w, const float* __restrict__ fc_b,
    float* __restrict__ prob,        // (NSEQ, NT)
    float* __restrict__ hout)        // (NSEQ, 32)
{
    __shared__ float s_h[4][HID];
    const int wv   = threadIdx.x >> 6;
    const int lane = threadIdx.x & 63;
    const int j    = lane & 31;
    const int half = lane >> 5;
    const size_t n = (size_t)blockIdx.x*4 + wv;    // 7696 = 4*1924

    const float4 wi0 = *(const float4*)(w_ih + (     j)*16 + half*8);
    const float4 wi1 = *(const float4*)(w_ih + (     j)*16 + half*8 + 4);
    const float4 wz0 = *(const float4*)(w_ih + (32 + j)*16 + half*8);
    const float4 wz1 = *(const float4*)(w_ih + (32 + j)*16 + half*8 + 4);
    const float4 wn0 = *(const float4*)(w_ih + (64 + j)*16 + half*8);
    const float4 wn1 = *(const float4*)(w_ih + (64 + j)*16 + half*8 + 4);

    const float* hrp  = w_hh + (     j)*32 + half*16;
    const float* hzp  = w_hh + (32 + j)*32 + half*16;
    const float* hnp_ = w_hh + (64 + j)*32 + half*16;
    const float4 hw0 = *(const float4*)(hrp),      hw1 = *(const float4*)(hrp + 4);
    const float4 hw2 = *(const float4*)(hrp + 8),  hw3 = *(const float4*)(hrp + 12);
    const float4 zw0 = *(const float4*)(hzp),      zw1 = *(const float4*)(hzp + 4);
    const float4 zw2 = *(const float4*)(hzp + 8),  zw3 = *(const float4*)(hzp + 12);
    const float4 nw0 = *(const float4*)(hnp_),     nw1 = *(const float4*)(hnp_ + 4);
    const float4 nw2 = *(const float4*)(hnp_ + 8), nw3 = *(const float4*)(hnp_ + 12);

    const float brr  = b_ih[j]      + b_hh[j];
    const float bzz  = b_ih[32 + j] + b_hh[32 + j];
    const float bin_ = b_ih[64 + j];
    const float bhn  = b_hh[64 + j];
    const float fw = fc_w[j];
    const float fb = fc_b[0];

    float h = h0[n*HID + j];
    if (half == 0) s_h[wv][j] = h;
    __builtin_amdgcn_wave_barrier();

    const float* xb = xin + (size_t)n*NT*CH + half*8;
    float4 cx0 = *(const float4*)(xb);
    float4 cx1 = *(const float4*)(xb + 4);
    float4 px0 = *(const float4*)(xb + 16);
    float4 px1 = *(const float4*)(xb + 20);

    // software-pipelined h read (for t=0)
    const float4* hp = (const float4*)&s_h[wv][half*16];
    float4 h0v = hp[0], h1v = hp[1], h2v = hp[2], h3v = hp[3];

    for (int t = 0; t < NT; t++) {
        const int t2 = (t + 2 < NT) ? t + 2 : NT - 1;
        const float4 fx0 = *(const float4*)(xb + t2*16);
        const float4 fx1 = *(const float4*)(xb + t2*16 + 4);

        // x partials (off the h critical path)
        float xr = 0.f, xz = 0.f, xnp = 0.f;
        DOT4(xr, wi0, cx0);  DOT4(xr, wi1, cx1);
        DOT4(xz, wz0, cx0);  DOT4(xz, wz1, cx1);
        DOT4(xnp, wn0, cx0); DOT4(xnp, wn1, cx1);

        // h partials
        float hr = 0.f, hz = 0.f, hn = 0.f;
        DOT4(hr, hw0, h0v); DOT4(hr, hw1, h1v); DOT4(hr, hw2, h2v); DOT4(hr, hw3, h3v);
        DOT4(hz, zw0, h0v); DOT4(hz, zw1, h1v); DOT4(hz, zw2, h2v); DOT4(hz, zw3, h3v);
        DOT4(hn, nw0, h0v); DOT4(hn, nw1, h1v); DOT4(hn, nw2, h2v); DOT4(hn, nw3, h3v);

        // combine halves
        float prz = xr + hr;  prz += __shfl_xor(prz, 32);
        float pzz = xz + hz;  pzz += __shfl_xor(pzz, 32);
        float xn  = xnp + __shfl_xor(xnp, 32) + bin_;
        float hnn = hn  + __shfl_xor(hn, 32)  + bhn;

        const float r = sig_(prz + brr);
        const float z = sig_(pzz + bzz);
        const float aa = xn + r*hnn;
        const float nn = 2.f*sig_(2.f*aa) - 1.f;       // tanh
        const float hnew = (1.f - z)*nn + z*h;

        // publish h for next step FIRST (critical path), then read it back
        if (half == 0) s_h[wv][j] = hnew;
        __builtin_amdgcn_wave_barrier();
        h0v = hp[0]; h1v = hp[1]; h2v = hp[2]; h3v = hp[3];

        // FC + sigmoid: off the recurrence critical path now
        float pa = fw * hnew;
        pa += __shfl_xor(pa, 1);
        pa += __shfl_xor(pa, 2);
        pa += __shfl_xor(pa, 4);
        pa += __shfl_xor(pa, 8);
        pa += __shfl_xor(pa, 16);
        if (lane == 0) prob[n*(size_t)NT + t] = sig_(pa + fb);

        h = hnew;
        cx0 = px0; cx1 = px1; px0 = fx0; px1 = fx1;
    }

    if (half == 0) hout[n*HID + j] = h;
}

// -------------------------------------------------------------------------
extern "C" void kernel_launch(void* const* d_in, const int* in_sizes, int n_in,
                              void* d_out, int out_size, void* d_ws, size_t ws_size,
                              hipStream_t stream)
{
    const float* feat = (const float*)d_in[0];
    const float* h0   = (const float*)d_in[1];
    const float* w1   = (const float*)d_in[2];
    const float* b1   = (const float*)d_in[3];
    const float* a1   = (const float*)d_in[4];
    const float* w2   = (const float*)d_in[5];
    const float* b2   = (const float*)d_in[6];
    const float* a2   = (const float*)d_in[7];
    const float* wih  = (const float*)d_in[8];
    const float* whh  = (const float*)d_in[9];
    const float* bih  = (const float*)d_in[10];
    const float* bhh  = (const float*)d_in[11];
    const float* fcw  = (const float*)d_in[12];
    const float* fcb  = (const float*)d_in[13];

    float* xbuf = (float*)d_ws;                    // NSEQ*NT*16 floats = 246.3 MB
    float* prob = (float*)d_out;                   // (B, F, T)
    float* hout = prob + (size_t)NSEQ*NT;          // (1, NSEQ, 32)

    dim3 cgrid(NB, 31, 2);
    conv_kernel<<<cgrid, 256, 0, stream>>>(feat, w1, b1, a1, w2, b2, a2, xbuf);
    gru_kernel<<<NSEQ/4, 256, 0, stream>>>(xbuf, h0, wih, whh, bih, bhh, fcw, fcb, prob, hout);
}

// Round 7
// 2405.156 us; speedup vs baseline: 6.7804x; 1.0001x over previous
//
#include <hip/hip_runtime.h>

#define NF 481
#define NT 500
#define CH 16
#define HID 32
#define NB 16
#define NSEQ (NB*NF)   // 7696

__device__ __forceinline__ float sig_(float v) { return 1.0f / (1.0f + __expf(-v)); }

__device__ __forceinline__ float4 prelu4(float4 v, float a) {
    v.x = (v.x >= 0.f) ? v.x : a*v.x;
    v.y = (v.y >= 0.f) ? v.y : a*v.y;
    v.z = (v.z >= 0.f) ? v.z : a*v.z;
    v.w = (v.w >= 0.f) ? v.w : a*v.w;
    return v;
}

// pin a float4 in VGPRs: opaque to the optimizer -> cannot rematerialize
#define PIN4(V) asm volatile("" : "+v"((V).x), "+v"((V).y), "+v"((V).z), "+v"((V).w))

#define CONV1V(OFF)                                      \
    q0.x = fmaf(w1[(OFF) +  0*36], v, q0.x);             \
    q0.y = fmaf(w1[(OFF) +  1*36], v, q0.y);             \
    q0.z = fmaf(w1[(OFF) +  2*36], v, q0.z);             \
    q0.w = fmaf(w1[(OFF) +  3*36], v, q0.w);             \
    q1.x = fmaf(w1[(OFF) +  4*36], v, q1.x);             \
    q1.y = fmaf(w1[(OFF) +  5*36], v, q1.y);             \
    q1.z = fmaf(w1[(OFF) +  6*36], v, q1.z);             \
    q1.w = fmaf(w1[(OFF) +  7*36], v, q1.w);             \
    q2.x = fmaf(w1[(OFF) +  8*36], v, q2.x);             \
    q2.y = fmaf(w1[(OFF) +  9*36], v, q2.y);             \
    q2.z = fmaf(w1[(OFF) + 10*36], v, q2.z);             \
    q2.w = fmaf(w1[(OFF) + 11*36], v, q2.w);             \
    q3.x = fmaf(w1[(OFF) + 12*36], v, q3.x);             \
    q3.y = fmaf(w1[(OFF) + 13*36], v, q3.y);             \
    q3.z = fmaf(w1[(OFF) + 14*36], v, q3.z);             \
    q3.w = fmaf(w1[(OFF) + 15*36], v, q3.w)

#define CONV2Y(YV, CI)                                   \
    a0.x = fmaf(w2p[(( 0*16+(CI))*5)], YV, a0.x);        \
    a0.y = fmaf(w2p[(( 1*16+(CI))*5)], YV, a0.y);        \
    a0.z = fmaf(w2p[(( 2*16+(CI))*5)], YV, a0.z);        \
    a0.w = fmaf(w2p[(( 3*16+(CI))*5)], YV, a0.w);        \
    a1.x = fmaf(w2p[(( 4*16+(CI))*5)], YV, a1.x);        \
    a1.y = fmaf(w2p[(( 5*16+(CI))*5)], YV, a1.y);        \
    a1.z = fmaf(w2p[(( 6*16+(CI))*5)], YV, a1.z);        \
    a1.w = fmaf(w2p[(( 7*16+(CI))*5)], YV, a1.w);        \
    a2.x = fmaf(w2p[(( 8*16+(CI))*5)], YV, a2.x);        \
    a2.y = fmaf(w2p[(( 9*16+(CI))*5)], YV, a2.y);        \
    a2.z = fmaf(w2p[((10*16+(CI))*5)], YV, a2.z);        \
    a2.w = fmaf(w2p[((11*16+(CI))*5)], YV, a2.w);        \
    a3.x = fmaf(w2p[((12*16+(CI))*5)], YV, a3.x);        \
    a3.y = fmaf(w2p[((13*16+(CI))*5)], YV, a3.y);        \
    a3.z = fmaf(w2p[((14*16+(CI))*5)], YV, a3.z);        \
    a3.w = fmaf(w2p[((15*16+(CI))*5)], YV, a3.w)

// -------------------------------------------------------------------------
// Conv (unchanged from R5/R6 — clean counters): register-only direct conv.
// -------------------------------------------------------------------------
__global__ __launch_bounds__(256) void conv_kernel(
    const float* __restrict__ feat,
    const float* __restrict__ w1, const float* __restrict__ b1, const float* __restrict__ a1p,
    const float* __restrict__ w2, const float* __restrict__ b2, const float* __restrict__ a2p,
    float* __restrict__ xout)
{
    const int b    = blockIdx.x;
    const int f0   = blockIdx.y * 16;
    const int tz   = blockIdx.z;
    const int wv   = threadIdx.x >> 6;
    const int lane = threadIdx.x & 63;
    const float al1 = a1p[0], al2 = a2p[0];

    const float4 bb1a = *(const float4*)(b1);
    const float4 bb1b = *(const float4*)(b1 + 4);
    const float4 bb1c = *(const float4*)(b1 + 8);
    const float4 bb1d = *(const float4*)(b1 + 12);
    const float4 bb2a = *(const float4*)(b2);
    const float4 bb2b = *(const float4*)(b2 + 4);
    const float4 bb2c = *(const float4*)(b2 + 8);
    const float4 bb2d = *(const float4*)(b2 + 12);

    #pragma unroll 1
    for (int fi = 0; fi < 4; fi++) {
        const int f = f0 + wv + fi*4;
        if (f >= NF) continue;
        const size_t nrow = ((size_t)b*NF + f) * (size_t)NT;

        #pragma unroll 1
        for (int t0 = tz*256; t0 < tz*256 + 256 && t0 < NT; t0 += 64) {
            const int t  = t0 + lane;
            const int tc = (t < NT) ? t : (NT - 1);

            float4 a0 = bb2a, a1 = bb2b, a2 = bb2c, a3 = bb2d;

            #pragma unroll 1
            for (int kk = 0; kk < 5; kk++) {
                const int fy = f + kk - 2;
                float4 q0, q1, q2, q3;
                if (fy >= 0 && fy < NF) {
                    q0 = bb1a; q1 = bb1b; q2 = bb1c; q3 = bb1d;
                    #pragma unroll
                    for (int d = 0; d < 4; d++) {
                        const float* frow = feat + ((size_t)(b*4 + d)*NF)*NT;
                        #pragma unroll
                        for (int k1 = 0; k1 < 9; k1++) {
                            const int gf = fy + k1 - 4;
                            if (gf >= 0 && gf < NF) {
                                const float v = frow[(size_t)gf*NT + tc];
                                CONV1V(d*9 + k1);
                            }
                        }
                    }
                    q0 = prelu4(q0, al1); q1 = prelu4(q1, al1);
                    q2 = prelu4(q2, al1); q3 = prelu4(q3, al1);
                } else {
                    q0 = make_float4(0.f,0.f,0.f,0.f);
                    q1 = q0; q2 = q0; q3 = q0;
                }
                const float* w2p = w2 + kk;
                CONV2Y(q0.x,  0); CONV2Y(q0.y,  1); CONV2Y(q0.z,  2); CONV2Y(q0.w,  3);
                CONV2Y(q1.x,  4); CONV2Y(q1.y,  5); CONV2Y(q1.z,  6); CONV2Y(q1.w,  7);
                CONV2Y(q2.x,  8); CONV2Y(q2.y,  9); CONV2Y(q2.z, 10); CONV2Y(q2.w, 11);
                CONV2Y(q3.x, 12); CONV2Y(q3.y, 13); CONV2Y(q3.z, 14); CONV2Y(q3.w, 15);
            }

            if (t < NT) {
                float* op = xout + (nrow + t)*CH;
                *(float4*)(op     ) = prelu4(a0, al2);
                *(float4*)(op +  4) = prelu4(a1, al2);
                *(float4*)(op +  8) = prelu4(a2, al2);
                *(float4*)(op + 12) = prelu4(a3, al2);
            }
        }
    }
}

// -------------------------------------------------------------------------
// GRU + FC + sigmoid.  One wave/sequence; lane (j, half).
// R6 lesson: compiler REMATERIALIZED the 18 weight loads every t-step
// (VGPR_Count=72 — weights not resident; ~370 inst/step vs ~110 counted).
// Fix: PIN4 empty-asm makes each weight opaque -> must stay live in VGPRs.
// launch_bounds(256) plain -> VGPR cap 256, ~150 used -> 3 waves/SIMD.
// -------------------------------------------------------------------------
#define DOT4(acc, W, V)                             \
    acc = fmaf((W).x, (V).x, acc);                  \
    acc = fmaf((W).y, (V).y, acc);                  \
    acc = fmaf((W).z, (V).z, acc);                  \
    acc = fmaf((W).w, (V).w, acc)

__global__ __launch_bounds__(256) void gru_kernel(
    const float* __restrict__ xin,   // (NSEQ, NT, 16)
    const float* __restrict__ h0,    // (NSEQ, 32)
    const float* __restrict__ w_ih,  // (96, 16)
    const float* __restrict__ w_hh,  // (96, 32)
    const float* __restrict__ b_ih, const float* __restrict__ b_hh,
    const float* __restrict__ fc_w, const float* __restrict__ fc_b,
    float* __restrict__ prob,        // (NSEQ, NT)
    float* __restrict__ hout)        // (NSEQ, 32)
{
    __shared__ float s_h[4][HID];
    const int wv   = threadIdx.x >> 6;
    const int lane = threadIdx.x & 63;
    const int j    = lane & 31;
    const int half = lane >> 5;
    const size_t n = (size_t)blockIdx.x*4 + wv;    // 7696 = 4*1924

    float4 wi0 = *(const float4*)(w_ih + (     j)*16 + half*8);
    float4 wi1 = *(const float4*)(w_ih + (     j)*16 + half*8 + 4);
    float4 wz0 = *(const float4*)(w_ih + (32 + j)*16 + half*8);
    float4 wz1 = *(const float4*)(w_ih + (32 + j)*16 + half*8 + 4);
    float4 wn0 = *(const float4*)(w_ih + (64 + j)*16 + half*8);
    float4 wn1 = *(const float4*)(w_ih + (64 + j)*16 + half*8 + 4);
    PIN4(wi0); PIN4(wi1); PIN4(wz0); PIN4(wz1); PIN4(wn0); PIN4(wn1);

    const float* hrp  = w_hh + (     j)*32 + half*16;
    const float* hzp  = w_hh + (32 + j)*32 + half*16;
    const float* hnp_ = w_hh + (64 + j)*32 + half*16;
    float4 hw0 = *(const float4*)(hrp),      hw1 = *(const float4*)(hrp + 4);
    float4 hw2 = *(const float4*)(hrp + 8),  hw3 = *(const float4*)(hrp + 12);
    float4 zw0 = *(const float4*)(hzp),      zw1 = *(const float4*)(hzp + 4);
    float4 zw2 = *(const float4*)(hzp + 8),  zw3 = *(const float4*)(hzp + 12);
    float4 nw0 = *(const float4*)(hnp_),     nw1 = *(const float4*)(hnp_ + 4);
    float4 nw2 = *(const float4*)(hnp_ + 8), nw3 = *(const float4*)(hnp_ + 12);
    PIN4(hw0); PIN4(hw1); PIN4(hw2); PIN4(hw3);
    PIN4(zw0); PIN4(zw1); PIN4(zw2); PIN4(zw3);
    PIN4(nw0); PIN4(nw1); PIN4(nw2); PIN4(nw3);

    float brr  = b_ih[j]      + b_hh[j];
    float bzz  = b_ih[32 + j] + b_hh[32 + j];
    float bin_ = b_ih[64 + j];
    float bhn  = b_hh[64 + j];
    float fw = fc_w[j];
    const float fb = fc_b[0];
    asm volatile("" : "+v"(brr), "+v"(bzz), "+v"(bin_), "+v"(bhn), "+v"(fw));

    float h = h0[n*HID + j];
    if (half == 0) s_h[wv][j] = h;
    __builtin_amdgcn_wave_barrier();

    const float* xb = xin + (size_t)n*NT*CH + half*8;
    float4 cx0 = *(const float4*)(xb);
    float4 cx1 = *(const float4*)(xb + 4);
    float4 px0 = *(const float4*)(xb + 16);
    float4 px1 = *(const float4*)(xb + 20);

    // software-pipelined h read (for t=0)
    const float4* hp = (const float4*)&s_h[wv][half*16];
    float4 h0v = hp[0], h1v = hp[1], h2v = hp[2], h3v = hp[3];

    for (int t = 0; t < NT; t++) {
        const int t2 = (t + 2 < NT) ? t + 2 : NT - 1;
        const float4 fx0 = *(const float4*)(xb + t2*16);
        const float4 fx1 = *(const float4*)(xb + t2*16 + 4);

        // x partials (off the h critical path)
        float xr = 0.f, xz = 0.f, xnp = 0.f;
        DOT4(xr, wi0, cx0);  DOT4(xr, wi1, cx1);
        DOT4(xz, wz0, cx0);  DOT4(xz, wz1, cx1);
        DOT4(xnp, wn0, cx0); DOT4(xnp, wn1, cx1);

        // h partials
        float hr = 0.f, hz = 0.f, hn = 0.f;
        DOT4(hr, hw0, h0v); DOT4(hr, hw1, h1v); DOT4(hr, hw2, h2v); DOT4(hr, hw3, h3v);
        DOT4(hz, zw0, h0v); DOT4(hz, zw1, h1v); DOT4(hz, zw2, h2v); DOT4(hz, zw3, h3v);
        DOT4(hn, nw0, h0v); DOT4(hn, nw1, h1v); DOT4(hn, nw2, h2v); DOT4(hn, nw3, h3v);

        // combine halves
        float prz = xr + hr;  prz += __shfl_xor(prz, 32);
        float pzz = xz + hz;  pzz += __shfl_xor(pzz, 32);
        float xn  = xnp + __shfl_xor(xnp, 32) + bin_;
        float hnn = hn  + __shfl_xor(hn, 32)  + bhn;

        const float r = sig_(prz + brr);
        const float z = sig_(pzz + bzz);
        const float aa = xn + r*hnn;
        const float nn = 2.f*sig_(2.f*aa) - 1.f;       // tanh
        const float hnew = (1.f - z)*nn + z*h;

        // publish h for next step FIRST (critical path), then read it back
        if (half == 0) s_h[wv][j] = hnew;
        __builtin_amdgcn_wave_barrier();
        h0v = hp[0]; h1v = hp[1]; h2v = hp[2]; h3v = hp[3];

        // FC + sigmoid: off the recurrence critical path
        float pa = fw * hnew;
        pa += __shfl_xor(pa, 1);
        pa += __shfl_xor(pa, 2);
        pa += __shfl_xor(pa, 4);
        pa += __shfl_xor(pa, 8);
        pa += __shfl_xor(pa, 16);
        if (lane == 0) prob[n*(size_t)NT + t] = sig_(pa + fb);

        h = hnew;
        cx0 = px0; cx1 = px1; px0 = fx0; px1 = fx1;
    }

    if (half == 0) hout[n*HID + j] = h;
}

// -------------------------------------------------------------------------
extern "C" void kernel_launch(void* const* d_in, const int* in_sizes, int n_in,
                              void* d_out, int out_size, void* d_ws, size_t ws_size,
                              hipStream_t stream)
{
    const float* feat = (const float*)d_in[0];
    const float* h0   = (const float*)d_in[1];
    const float* w1   = (const float*)d_in[2];
    const float* b1   = (const float*)d_in[3];
    const float* a1   = (const float*)d_in[4];
    const float* w2   = (const float*)d_in[5];
    const float* b2   = (const float*)d_in[6];
    const float* a2   = (const float*)d_in[7];
    const float* wih  = (const float*)d_in[8];
    const float* whh  = (const float*)d_in[9];
    const float* bih  = (const float*)d_in[10];
    const float* bhh  = (const float*)d_in[11];
    const float* fcw  = (const float*)d_in[12];
    const float* fcb  = (const float*)d_in[13];

    float* xbuf = (float*)d_ws;                    // NSEQ*NT*16 floats = 246.3 MB
    float* prob = (float*)d_out;                   // (B, F, T)
    float* hout = prob + (size_t)NSEQ*NT;          // (1, NSEQ, 32)

    dim3 cgrid(NB, 31, 2);
    conv_kernel<<<cgrid, 256, 0, stream>>>(feat, w1, b1, a1, w2, b2, a2, xbuf);
    gru_kernel<<<NSEQ/4, 256, 0, stream>>>(xbuf, h0, wih, whh, bih, bhh, fcw, fcb, prob, hout);
}

// Round 8
// 1959.642 us; speedup vs baseline: 8.3219x; 1.2273x over previous
//
#include <hip/hip_runtime.h>

#define NF 481
#define NT 500
#define CH 16
#define HID 32
#define NB 16
#define NSEQ (NB*NF)   // 7696

typedef __attribute__((ext_vector_type(8))) short short8;
typedef __attribute__((ext_vector_type(4))) float f32x4;

__device__ __forceinline__ float sig_(float v) { return 1.0f / (1.0f + __expf(-v)); }

__device__ __forceinline__ unsigned short f2bf(float f) {
    unsigned u = __float_as_uint(f);
    u = (u + 0x7fffu + ((u >> 16) & 1u)) >> 16;   // RNE
    return (unsigned short)u;
}
__device__ __forceinline__ unsigned int pk2(float a, float b) {
    return (unsigned int)f2bf(a) | ((unsigned int)f2bf(b) << 16);
}

__device__ __forceinline__ float4 prelu4(float4 v, float a) {
    v.x = (v.x >= 0.f) ? v.x : a*v.x;
    v.y = (v.y >= 0.f) ? v.y : a*v.y;
    v.z = (v.z >= 0.f) ? v.z : a*v.z;
    v.w = (v.w >= 0.f) ? v.w : a*v.w;
    return v;
}

#define CONV1V(OFF)                                      \
    q0.x = fmaf(w1[(OFF) +  0*36], v, q0.x);             \
    q0.y = fmaf(w1[(OFF) +  1*36], v, q0.y);             \
    q0.z = fmaf(w1[(OFF) +  2*36], v, q0.z);             \
    q0.w = fmaf(w1[(OFF) +  3*36], v, q0.w);             \
    q1.x = fmaf(w1[(OFF) +  4*36], v, q1.x);             \
    q1.y = fmaf(w1[(OFF) +  5*36], v, q1.y);             \
    q1.z = fmaf(w1[(OFF) +  6*36], v, q1.z);             \
    q1.w = fmaf(w1[(OFF) +  7*36], v, q1.w);             \
    q2.x = fmaf(w1[(OFF) +  8*36], v, q2.x);             \
    q2.y = fmaf(w1[(OFF) +  9*36], v, q2.y);             \
    q2.z = fmaf(w1[(OFF) + 10*36], v, q2.z);             \
    q2.w = fmaf(w1[(OFF) + 11*36], v, q2.w);             \
    q3.x = fmaf(w1[(OFF) + 12*36], v, q3.x);             \
    q3.y = fmaf(w1[(OFF) + 13*36], v, q3.y);             \
    q3.z = fmaf(w1[(OFF) + 14*36], v, q3.z);             \
    q3.w = fmaf(w1[(OFF) + 15*36], v, q3.w)

#define CONV2Y(YV, CI)                                   \
    a0.x = fmaf(w2p[(( 0*16+(CI))*5)], YV, a0.x);        \
    a0.y = fmaf(w2p[(( 1*16+(CI))*5)], YV, a0.y);        \
    a0.z = fmaf(w2p[(( 2*16+(CI))*5)], YV, a0.z);        \
    a0.w = fmaf(w2p[(( 3*16+(CI))*5)], YV, a0.w);        \
    a1.x = fmaf(w2p[(( 4*16+(CI))*5)], YV, a1.x);        \
    a1.y = fmaf(w2p[(( 5*16+(CI))*5)], YV, a1.y);        \
    a1.z = fmaf(w2p[(( 6*16+(CI))*5)], YV, a1.z);        \
    a1.w = fmaf(w2p[(( 7*16+(CI))*5)], YV, a1.w);        \
    a2.x = fmaf(w2p[(( 8*16+(CI))*5)], YV, a2.x);        \
    a2.y = fmaf(w2p[(( 9*16+(CI))*5)], YV, a2.y);        \
    a2.z = fmaf(w2p[((10*16+(CI))*5)], YV, a2.z);        \
    a2.w = fmaf(w2p[((11*16+(CI))*5)], YV, a2.w);        \
    a3.x = fmaf(w2p[((12*16+(CI))*5)], YV, a3.x);        \
    a3.y = fmaf(w2p[((13*16+(CI))*5)], YV, a3.y);        \
    a3.z = fmaf(w2p[((14*16+(CI))*5)], YV, a3.z);        \
    a3.w = fmaf(w2p[((15*16+(CI))*5)], YV, a3.w)

// -------------------------------------------------------------------------
// Conv (R5 structure, clean counters). Only change: bf16 output (halves
// write traffic and the GRU's fetch).
// -------------------------------------------------------------------------
__global__ __launch_bounds__(256) void conv_kernel(
    const float* __restrict__ feat,
    const float* __restrict__ w1, const float* __restrict__ b1, const float* __restrict__ a1p,
    const float* __restrict__ w2, const float* __restrict__ b2, const float* __restrict__ a2p,
    unsigned short* __restrict__ xout)
{
    const int b    = blockIdx.x;
    const int f0   = blockIdx.y * 16;
    const int tz   = blockIdx.z;
    const int wv   = threadIdx.x >> 6;
    const int lane = threadIdx.x & 63;
    const float al1 = a1p[0], al2 = a2p[0];

    const float4 bb1a = *(const float4*)(b1);
    const float4 bb1b = *(const float4*)(b1 + 4);
    const float4 bb1c = *(const float4*)(b1 + 8);
    const float4 bb1d = *(const float4*)(b1 + 12);
    const float4 bb2a = *(const float4*)(b2);
    const float4 bb2b = *(const float4*)(b2 + 4);
    const float4 bb2c = *(const float4*)(b2 + 8);
    const float4 bb2d = *(const float4*)(b2 + 12);

    #pragma unroll 1
    for (int fi = 0; fi < 4; fi++) {
        const int f = f0 + wv + fi*4;
        if (f >= NF) continue;
        const size_t nrow = ((size_t)b*NF + f) * (size_t)NT;

        #pragma unroll 1
        for (int t0 = tz*256; t0 < tz*256 + 256 && t0 < NT; t0 += 64) {
            const int t  = t0 + lane;
            const int tc = (t < NT) ? t : (NT - 1);

            float4 a0 = bb2a, a1 = bb2b, a2 = bb2c, a3 = bb2d;

            #pragma unroll 1
            for (int kk = 0; kk < 5; kk++) {
                const int fy = f + kk - 2;
                float4 q0, q1, q2, q3;
                if (fy >= 0 && fy < NF) {
                    q0 = bb1a; q1 = bb1b; q2 = bb1c; q3 = bb1d;
                    #pragma unroll
                    for (int d = 0; d < 4; d++) {
                        const float* frow = feat + ((size_t)(b*4 + d)*NF)*NT;
                        #pragma unroll
                        for (int k1 = 0; k1 < 9; k1++) {
                            const int gf = fy + k1 - 4;
                            if (gf >= 0 && gf < NF) {
                                const float v = frow[(size_t)gf*NT + tc];
                                CONV1V(d*9 + k1);
                            }
                        }
                    }
                    q0 = prelu4(q0, al1); q1 = prelu4(q1, al1);
                    q2 = prelu4(q2, al1); q3 = prelu4(q3, al1);
                } else {
                    q0 = make_float4(0.f,0.f,0.f,0.f);
                    q1 = q0; q2 = q0; q3 = q0;
                }
                const float* w2p = w2 + kk;
                CONV2Y(q0.x,  0); CONV2Y(q0.y,  1); CONV2Y(q0.z,  2); CONV2Y(q0.w,  3);
                CONV2Y(q1.x,  4); CONV2Y(q1.y,  5); CONV2Y(q1.z,  6); CONV2Y(q1.w,  7);
                CONV2Y(q2.x,  8); CONV2Y(q2.y,  9); CONV2Y(q2.z, 10); CONV2Y(q2.w, 11);
                CONV2Y(q3.x, 12); CONV2Y(q3.y, 13); CONV2Y(q3.z, 14); CONV2Y(q3.w, 15);
            }

            if (t < NT) {
                a0 = prelu4(a0, al2); a1 = prelu4(a1, al2);
                a2 = prelu4(a2, al2); a3 = prelu4(a3, al2);
                unsigned short* op = xout + (nrow + t)*CH;
                uint4 u0 = make_uint4(pk2(a0.x,a0.y), pk2(a0.z,a0.w),
                                      pk2(a1.x,a1.y), pk2(a1.z,a1.w));
                uint4 u1 = make_uint4(pk2(a2.x,a2.y), pk2(a2.z,a2.w),
                                      pk2(a3.x,a3.y), pk2(a3.z,a3.w));
                *(uint4*)(op)     = u0;
                *(uint4*)(op + 8) = u1;
            }
        }
    }
}

// -------------------------------------------------------------------------
// GRU via MFMA.  One wave = 16 sequences.  Per step:
//   pre[16 x 128] = A[16 x 64] * B[64 x 128]   (14x mfma_f32_16x16x32_bf16)
// A = [x_t(16) | h(32) | 0(16)] per seq (bf16, staged in LDS, stride 72).
// B columns: r(32) | z(32) | xn(32) | hn(32); xn gets only K-chunk0.
// h recurrence kept in fp32 registers (C-layout: lane c=l&15, quad=l>>4
// owns units {c, c+16} of seqs quad*4+reg).  Weights live once per wave
// as B-fragments -> no per-lane weight pressure (R5-R7 allocator fight).
// -------------------------------------------------------------------------
__global__ __launch_bounds__(64) void gru_kernel(
    const unsigned short* __restrict__ xin,  // (NSEQ, NT, 16) bf16
    const float* __restrict__ h0,    // (NSEQ, 32)
    const float* __restrict__ w_ih,  // (96, 16)
    const float* __restrict__ w_hh,  // (96, 32)
    const float* __restrict__ b_ih, const float* __restrict__ b_hh,
    const float* __restrict__ fc_w, const float* __restrict__ fc_b,
    float* __restrict__ prob,        // (NSEQ, NT)
    float* __restrict__ hout)        // (NSEQ, 32)
{
    __shared__ unsigned short sv[16*72];     // [seq][72] bf16; stride 144B
    const int lane = threadIdx.x & 63;
    const int c    = lane & 15;
    const int quad = lane >> 4;
    const int base = blockIdx.x * 16;        // 481 blocks x 16 seq = 7696

    // ---- B fragments (one-time gather; wave-shared weights) ----
    #define WPRIME(G, K) (                                                     \
        ((G) < 64) ? ( ((K) < 16) ? w_ih[(G)*16 + (K)]                         \
                     : ((K) < 48) ? w_hh[(G)*32 + (K) - 16] : 0.f )            \
      : ((G) < 96) ? ( ((K) < 16) ? w_ih[((G)-32)*16 + (K)] : 0.f )            \
      : ( ((K) >= 16 && (K) < 48) ? w_hh[((G)-64)*32 + (K) - 16] : 0.f ) )
    // note: xn rows are w_ih rows 64..95 -> (G)-32 maps 64..95->32.. wait:
    // G in [64,96): w_ih row = 64 + (G-64) = G  -> use w_ih[(G)*16+K]? No:
    // simpler explicit below.
    #undef WPRIME

    #define MKB(DST, G, CK)                                                    \
        { _Pragma("unroll") for (int j = 0; j < 8; j++) {                      \
            const int k = (CK)*32 + quad*8 + j;                                \
            const int g = (G);                                                 \
            float wv_;                                                         \
            if (g < 64)      wv_ = (k < 16) ? w_ih[g*16 + k]                   \
                                  : (k < 48) ? w_hh[g*32 + k - 16] : 0.f;      \
            else if (g < 96) wv_ = (k < 16) ? w_ih[g*16 + k] : 0.f;            \
            else             wv_ = (k >= 16 && k < 48)                         \
                                  ? w_hh[(g-32)*32 + k - 16] : 0.f;            \
            DST[j] = (short)f2bf(wv_); } }

    short8 B0a, B0b, B1a, B1b, B2a, B2b, B3a, B3b, B4a, B5a, B6a, B6b, B7a, B7b;
    MKB(B0a,       c, 0); MKB(B0b,       c, 1);   // r  units 0..15
    MKB(B1a,  16 + c, 0); MKB(B1b,  16 + c, 1);   // r  units 16..31
    MKB(B2a,  32 + c, 0); MKB(B2b,  32 + c, 1);   // z
    MKB(B3a,  48 + c, 0); MKB(B3b,  48 + c, 1);
    MKB(B4a,  64 + c, 0);                          // xn (chunk1 all-zero)
    MKB(B5a,  80 + c, 0);
    MKB(B6a,  96 + c, 0); MKB(B6b,  96 + c, 1);   // hn
    MKB(B7a, 112 + c, 0); MKB(B7b, 112 + c, 1);

    // biases (accumulator init; n-gate biases stay separated)
    const float bi0 = b_ih[c]      + b_hh[c];
    const float bi1 = b_ih[16 + c] + b_hh[16 + c];
    const float bi2 = b_ih[32 + c] + b_hh[32 + c];
    const float bi3 = b_ih[48 + c] + b_hh[48 + c];
    const float bi4 = b_ih[64 + c];
    const float bi5 = b_ih[80 + c];
    const float bi6 = b_hh[64 + c];
    const float bi7 = b_hh[80 + c];
    const float fcw0 = fc_w[c], fcw1 = fc_w[16 + c];
    const float fb = fc_b[0];

    // fp32 hidden state (C-layout: seqs quad*4+0..3, units c and 16+c)
    float hp00 = h0[(size_t)(base + quad*4 + 0)*HID + c];
    float hp01 = h0[(size_t)(base + quad*4 + 0)*HID + 16 + c];
    float hp10 = h0[(size_t)(base + quad*4 + 1)*HID + c];
    float hp11 = h0[(size_t)(base + quad*4 + 1)*HID + 16 + c];
    float hp20 = h0[(size_t)(base + quad*4 + 2)*HID + c];
    float hp21 = h0[(size_t)(base + quad*4 + 2)*HID + 16 + c];
    float hp30 = h0[(size_t)(base + quad*4 + 3)*HID + c];
    float hp31 = h0[(size_t)(base + quad*4 + 3)*HID + 16 + c];

    // ---- init LDS v-buffer ----
    // zero pad k=48..63
    *(uint2*)&sv[(lane >> 2)*72 + 48 + (lane & 3)*4] = make_uint2(0u, 0u);
    // h0 -> bf16
    sv[(quad*4 + 0)*72 + 16 + c] = f2bf(hp00);  sv[(quad*4 + 0)*72 + 32 + c] = f2bf(hp01);
    sv[(quad*4 + 1)*72 + 16 + c] = f2bf(hp10);  sv[(quad*4 + 1)*72 + 32 + c] = f2bf(hp11);
    sv[(quad*4 + 2)*72 + 16 + c] = f2bf(hp20);  sv[(quad*4 + 2)*72 + 32 + c] = f2bf(hp21);
    sv[(quad*4 + 3)*72 + 16 + c] = f2bf(hp30);  sv[(quad*4 + 3)*72 + 32 + c] = f2bf(hp31);
    // x(t=0): lane loads 4 bf16 of seq lane>>2
    const unsigned short* xrow = xin + ((size_t)(base + (lane >> 2)))*NT*CH + (lane & 3)*4;
    uint2 nx = *(const uint2*)(xrow);
    *(uint2*)&sv[(lane >> 2)*72 + (lane & 3)*4] = nx;
    __builtin_amdgcn_wave_barrier();

    #define GSTEP(R, HP0, HP1)                                                 \
        {                                                                      \
            const float rr0 = sig_(acc0[R]);                                   \
            const float rr1 = sig_(acc1[R]);                                   \
            const float zz0 = sig_(acc2[R]);                                   \
            const float zz1 = sig_(acc3[R]);                                   \
            const float aa0 = fmaf(rr0, acc6[R], acc4[R]);                     \
            const float aa1 = fmaf(rr1, acc7[R], acc5[R]);                     \
            const float nn0 = 2.f*sig_(2.f*aa0) - 1.f;                         \
            const float nn1 = 2.f*sig_(2.f*aa1) - 1.f;                         \
            HP0 = nn0 + zz0*(HP0 - nn0);                                       \
            HP1 = nn1 + zz1*(HP1 - nn1);                                       \
            sv[(quad*4 + (R))*72 + 16 + c] = f2bf(HP0);                        \
            sv[(quad*4 + (R))*72 + 32 + c] = f2bf(HP1);                        \
            float pa = fmaf(fcw1, HP1, fcw0*HP0);                              \
            pa += __shfl_xor(pa, 1);                                           \
            pa += __shfl_xor(pa, 2);                                           \
            pa += __shfl_xor(pa, 4);                                           \
            pa += __shfl_xor(pa, 8);                                           \
            if (c == 0)                                                        \
                prob[(size_t)(base + quad*4 + (R))*NT + t] = sig_(pa + fb);    \
        }

    for (int t = 0; t < NT; t++) {
        // A fragments (A[m= c][k = quad*8+j]); reads x_t, h_t from LDS
        const short8 a0 = *(const short8*)&sv[c*72 + quad*8];        // k 0..31
        const short8 a1 = *(const short8*)&sv[c*72 + 32 + quad*8];   // k 32..63
        __builtin_amdgcn_wave_barrier();   // pin reads before this iter's writes

        // prefetch next x (latency covered by MFMA+epilogue)
        const int tn = (t + 1 < NT) ? t + 1 : NT - 1;
        nx = *(const uint2*)(xrow + (size_t)tn*CH);

        f32x4 acc0 = {bi0, bi0, bi0, bi0};
        f32x4 acc1 = {bi1, bi1, bi1, bi1};
        f32x4 acc2 = {bi2, bi2, bi2, bi2};
        f32x4 acc3 = {bi3, bi3, bi3, bi3};
        f32x4 acc4 = {bi4, bi4, bi4, bi4};
        f32x4 acc5 = {bi5, bi5, bi5, bi5};
        f32x4 acc6 = {bi6, bi6, bi6, bi6};
        f32x4 acc7 = {bi7, bi7, bi7, bi7};

        acc0 = __builtin_amdgcn_mfma_f32_16x16x32_bf16(a0, B0a, acc0, 0, 0, 0);
        acc1 = __builtin_amdgcn_mfma_f32_16x16x32_bf16(a0, B1a, acc1, 0, 0, 0);
        acc2 = __builtin_amdgcn_mfma_f32_16x16x32_bf16(a0, B2a, acc2, 0, 0, 0);
        acc3 = __builtin_amdgcn_mfma_f32_16x16x32_bf16(a0, B3a, acc3, 0, 0, 0);
        acc4 = __builtin_amdgcn_mfma_f32_16x16x32_bf16(a0, B4a, acc4, 0, 0, 0);
        acc5 = __builtin_amdgcn_mfma_f32_16x16x32_bf16(a0, B5a, acc5, 0, 0, 0);
        acc6 = __builtin_amdgcn_mfma_f32_16x16x32_bf16(a0, B6a, acc6, 0, 0, 0);
        acc7 = __builtin_amdgcn_mfma_f32_16x16x32_bf16(a0, B7a, acc7, 0, 0, 0);
        acc0 = __builtin_amdgcn_mfma_f32_16x16x32_bf16(a1, B0b, acc0, 0, 0, 0);
        acc1 = __builtin_amdgcn_mfma_f32_16x16x32_bf16(a1, B1b, acc1, 0, 0, 0);
        acc2 = __builtin_amdgcn_mfma_f32_16x16x32_bf16(a1, B2b, acc2, 0, 0, 0);
        acc3 = __builtin_amdgcn_mfma_f32_16x16x32_bf16(a1, B3b, acc3, 0, 0, 0);
        acc6 = __builtin_amdgcn_mfma_f32_16x16x32_bf16(a1, B6b, acc6, 0, 0, 0);
        acc7 = __builtin_amdgcn_mfma_f32_16x16x32_bf16(a1, B7b, acc7, 0, 0, 0);

        GSTEP(0, hp00, hp01);
        GSTEP(1, hp10, hp11);
        GSTEP(2, hp20, hp21);
        GSTEP(3, hp30, hp31);

        // stage x_{t+1} (after this iter's A reads; program order + barrier)
        *(uint2*)&sv[(lane >> 2)*72 + (lane & 3)*4] = nx;
        __builtin_amdgcn_wave_barrier();
    }

    hout[(size_t)(base + quad*4 + 0)*HID + c]      = hp00;
    hout[(size_t)(base + quad*4 + 0)*HID + 16 + c] = hp01;
    hout[(size_t)(base + quad*4 + 1)*HID + c]      = hp10;
    hout[(size_t)(base + quad*4 + 1)*HID + 16 + c] = hp11;
    hout[(size_t)(base + quad*4 + 2)*HID + c]      = hp20;
    hout[(size_t)(base + quad*4 + 2)*HID + 16 + c] = hp21;
    hout[(size_t)(base + quad*4 + 3)*HID + c]      = hp30;
    hout[(size_t)(base + quad*4 + 3)*HID + 16 + c] = hp31;
}

// -------------------------------------------------------------------------
extern "C" void kernel_launch(void* const* d_in, const int* in_sizes, int n_in,
                              void* d_out, int out_size, void* d_ws, size_t ws_size,
                              hipStream_t stream)
{
    const float* feat = (const float*)d_in[0];
    const float* h0   = (const float*)d_in[1];
    const float* w1   = (const float*)d_in[2];
    const float* b1   = (const float*)d_in[3];
    const float* a1   = (const float*)d_in[4];
    const float* w2   = (const float*)d_in[5];
    const float* b2   = (const float*)d_in[6];
    const float* a2   = (const float*)d_in[7];
    const float* wih  = (const float*)d_in[8];
    const float* whh  = (const float*)d_in[9];
    const float* bih  = (const float*)d_in[10];
    const float* bhh  = (const float*)d_in[11];
    const float* fcw  = (const float*)d_in[12];
    const float* fcb  = (const float*)d_in[13];

    unsigned short* xbuf = (unsigned short*)d_ws;  // NSEQ*NT*16 bf16 = 123 MB
    float* prob = (float*)d_out;                   // (B, F, T)
    float* hout = prob + (size_t)NSEQ*NT;          // (1, NSEQ, 32)

    dim3 cgrid(NB, 31, 2);
    conv_kernel<<<cgrid, 256, 0, stream>>>(feat, w1, b1, a1, w2, b2, a2, xbuf);
    gru_kernel<<<NSEQ/16, 64, 0, stream>>>(xbuf, h0, wih, whh, bih, bhh, fcw, fcb, prob, hout);
}

// Round 9
// 1193.467 us; speedup vs baseline: 13.6644x; 1.6420x over previous
//
#include <hip/hip_runtime.h>

#define NF 481
#define NT 500
#define CH 16
#define HID 32
#define NB 16
#define NSEQ (NB*NF)   // 7696

typedef __attribute__((ext_vector_type(8))) short short8;
typedef __attribute__((ext_vector_type(4))) float f32x4;

__device__ __forceinline__ float sig_(float v) { return 1.0f / (1.0f + __expf(-v)); }

__device__ __forceinline__ unsigned short f2bf(float f) {
    unsigned u = __float_as_uint(f);
    u = (u + 0x7fffu + ((u >> 16) & 1u)) >> 16;   // RNE
    return (unsigned short)u;
}
__device__ __forceinline__ unsigned int pk2(float a, float b) {
    return (unsigned int)f2bf(a) | ((unsigned int)f2bf(b) << 16);
}
__device__ __forceinline__ float4 ubf4(uint2 u) {   // 4 bf16 -> 4 fp32
    float4 v;
    v.x = __uint_as_float(u.x << 16);
    v.y = __uint_as_float(u.x & 0xffff0000u);
    v.z = __uint_as_float(u.y << 16);
    v.w = __uint_as_float(u.y & 0xffff0000u);
    return v;
}
__device__ __forceinline__ float4 prelu4(float4 v, float a) {
    v.x = (v.x >= 0.f) ? v.x : a*v.x;
    v.y = (v.y >= 0.f) ? v.y : a*v.y;
    v.z = (v.z >= 0.f) ? v.z : a*v.z;
    v.w = (v.w >= 0.f) ? v.w : a*v.w;
    return v;
}

#define FMA4(Q, W, V)                     \
    Q.x = fmaf((W), (V).x, Q.x);          \
    Q.y = fmaf((W), (V).y, Q.y);          \
    Q.z = fmaf((W), (V).z, Q.z);          \
    Q.w = fmaf((W), (V).w, Q.w)

// -------------------------------------------------------------------------
// Pass 1: conv1(4->16,k9,p4) + PReLU -> y1 (b, f, ch, t) bf16.
// conv1 computed ONCE per column (R8 single-pass recomputed it 5x and
// re-issued ~2880 weight s_loads/strip -> VALUBusy 35%).
// Wave = one f; lane = 4 consecutive t (float4 feat loads).
// -------------------------------------------------------------------------
#define P1TAP(D, K1)                                                           \
    {                                                                          \
        const int gf = f + (K1) - 4;                                           \
        if (gf >= 0 && gf < NF) {                                              \
            const float4 v = *(const float4*)(feat +                           \
                ((size_t)(b*4 + (D))*NF + gf)*NT + tc0);                       \
            FMA4(q0,  w1[ 0*36 + (D)*9 + (K1)], v);                            \
            FMA4(q1,  w1[ 1*36 + (D)*9 + (K1)], v);                            \
            FMA4(q2,  w1[ 2*36 + (D)*9 + (K1)], v);                            \
            FMA4(q3,  w1[ 3*36 + (D)*9 + (K1)], v);                            \
            FMA4(q4,  w1[ 4*36 + (D)*9 + (K1)], v);                            \
            FMA4(q5,  w1[ 5*36 + (D)*9 + (K1)], v);                            \
            FMA4(q6,  w1[ 6*36 + (D)*9 + (K1)], v);                            \
            FMA4(q7,  w1[ 7*36 + (D)*9 + (K1)], v);                            \
            FMA4(q8,  w1[ 8*36 + (D)*9 + (K1)], v);                            \
            FMA4(q9,  w1[ 9*36 + (D)*9 + (K1)], v);                            \
            FMA4(q10, w1[10*36 + (D)*9 + (K1)], v);                            \
            FMA4(q11, w1[11*36 + (D)*9 + (K1)], v);                            \
            FMA4(q12, w1[12*36 + (D)*9 + (K1)], v);                            \
            FMA4(q13, w1[13*36 + (D)*9 + (K1)], v);                            \
            FMA4(q14, w1[14*36 + (D)*9 + (K1)], v);                            \
            FMA4(q15, w1[15*36 + (D)*9 + (K1)], v);                            \
        }                                                                      \
    }

__global__ __launch_bounds__(256) void conv1_kernel(
    const float* __restrict__ feat,
    const float* __restrict__ w1, const float* __restrict__ b1, const float* __restrict__ a1p,
    unsigned short* __restrict__ y1)
{
    const int b    = blockIdx.x;
    const int wv   = threadIdx.x >> 6;
    const int lane = threadIdx.x & 63;
    const int f    = blockIdx.y*4 + wv;
    if (f >= NF) return;                      // wave-uniform; no barriers used
    const int gt0  = blockIdx.z*256 + lane*4;
    const int tc0  = (gt0 <= NT-4) ? gt0 : (NT-4);
    const float al1 = a1p[0];

    float4 q0  = make_float4(b1[0],b1[0],b1[0],b1[0]);
    float4 q1  = make_float4(b1[1],b1[1],b1[1],b1[1]);
    float4 q2  = make_float4(b1[2],b1[2],b1[2],b1[2]);
    float4 q3  = make_float4(b1[3],b1[3],b1[3],b1[3]);
    float4 q4  = make_float4(b1[4],b1[4],b1[4],b1[4]);
    float4 q5  = make_float4(b1[5],b1[5],b1[5],b1[5]);
    float4 q6  = make_float4(b1[6],b1[6],b1[6],b1[6]);
    float4 q7  = make_float4(b1[7],b1[7],b1[7],b1[7]);
    float4 q8  = make_float4(b1[8],b1[8],b1[8],b1[8]);
    float4 q9  = make_float4(b1[9],b1[9],b1[9],b1[9]);
    float4 q10 = make_float4(b1[10],b1[10],b1[10],b1[10]);
    float4 q11 = make_float4(b1[11],b1[11],b1[11],b1[11]);
    float4 q12 = make_float4(b1[12],b1[12],b1[12],b1[12]);
    float4 q13 = make_float4(b1[13],b1[13],b1[13],b1[13]);
    float4 q14 = make_float4(b1[14],b1[14],b1[14],b1[14]);
    float4 q15 = make_float4(b1[15],b1[15],b1[15],b1[15]);

    #pragma unroll
    for (int d = 0; d < 4; d++) {
        P1TAP(d, 0); P1TAP(d, 1); P1TAP(d, 2); P1TAP(d, 3); P1TAP(d, 4);
        P1TAP(d, 5); P1TAP(d, 6); P1TAP(d, 7); P1TAP(d, 8);
    }

    if (gt0 < NT) {
        unsigned short* yb = y1 + ((size_t)(b*NF + f)*CH)*NT + gt0;
        q0  = prelu4(q0,  al1); q1  = prelu4(q1,  al1);
        q2  = prelu4(q2,  al1); q3  = prelu4(q3,  al1);
        q4  = prelu4(q4,  al1); q5  = prelu4(q5,  al1);
        q6  = prelu4(q6,  al1); q7  = prelu4(q7,  al1);
        q8  = prelu4(q8,  al1); q9  = prelu4(q9,  al1);
        q10 = prelu4(q10, al1); q11 = prelu4(q11, al1);
        q12 = prelu4(q12, al1); q13 = prelu4(q13, al1);
        q14 = prelu4(q14, al1); q15 = prelu4(q15, al1);
        *(uint2*)(yb +  0*NT) = make_uint2(pk2(q0.x, q0.y),  pk2(q0.z, q0.w));
        *(uint2*)(yb +  1*NT) = make_uint2(pk2(q1.x, q1.y),  pk2(q1.z, q1.w));
        *(uint2*)(yb +  2*NT) = make_uint2(pk2(q2.x, q2.y),  pk2(q2.z, q2.w));
        *(uint2*)(yb +  3*NT) = make_uint2(pk2(q3.x, q3.y),  pk2(q3.z, q3.w));
        *(uint2*)(yb +  4*NT) = make_uint2(pk2(q4.x, q4.y),  pk2(q4.z, q4.w));
        *(uint2*)(yb +  5*NT) = make_uint2(pk2(q5.x, q5.y),  pk2(q5.z, q5.w));
        *(uint2*)(yb +  6*NT) = make_uint2(pk2(q6.x, q6.y),  pk2(q6.z, q6.w));
        *(uint2*)(yb +  7*NT) = make_uint2(pk2(q7.x, q7.y),  pk2(q7.z, q7.w));
        *(uint2*)(yb +  8*NT) = make_uint2(pk2(q8.x, q8.y),  pk2(q8.z, q8.w));
        *(uint2*)(yb +  9*NT) = make_uint2(pk2(q9.x, q9.y),  pk2(q9.z, q9.w));
        *(uint2*)(yb + 10*NT) = make_uint2(pk2(q10.x,q10.y), pk2(q10.z,q10.w));
        *(uint2*)(yb + 11*NT) = make_uint2(pk2(q11.x,q11.y), pk2(q11.z,q11.w));
        *(uint2*)(yb + 12*NT) = make_uint2(pk2(q12.x,q12.y), pk2(q12.z,q12.w));
        *(uint2*)(yb + 13*NT) = make_uint2(pk2(q13.x,q13.y), pk2(q13.z,q13.w));
        *(uint2*)(yb + 14*NT) = make_uint2(pk2(q14.x,q14.y), pk2(q14.z,q14.w));
        *(uint2*)(yb + 15*NT) = make_uint2(pk2(q15.x,q15.y), pk2(q15.z,q15.w));
    }
}

// -------------------------------------------------------------------------
// Pass 2: conv2(16->16,k5,p2) + PReLU -> x (n, t, 16) bf16.
// Wave = one f; lane = 4 t.  y1 rows read as bf16x4 uint2.
// WB points at w2 + (0*16+ci)*5 + kk; out-ch stride 80.
// -------------------------------------------------------------------------
#define P2ROW(WB, V)                                                           \
    FMA4(a0,  (WB)[0],    V); FMA4(a1,  (WB)[80],   V);                        \
    FMA4(a2,  (WB)[160],  V); FMA4(a3,  (WB)[240],  V);                        \
    FMA4(a4,  (WB)[320],  V); FMA4(a5,  (WB)[400],  V);                        \
    FMA4(a6,  (WB)[480],  V); FMA4(a7,  (WB)[560],  V);                        \
    FMA4(a8,  (WB)[640],  V); FMA4(a9,  (WB)[720],  V);                        \
    FMA4(a10, (WB)[800],  V); FMA4(a11, (WB)[880],  V);                        \
    FMA4(a12, (WB)[960],  V); FMA4(a13, (WB)[1040], V);                        \
    FMA4(a14, (WB)[1120], V); FMA4(a15, (WB)[1200], V)

#define STX(E, COMP)                                                           \
    *(uint4*)(op + (E)*CH) = make_uint4(                                       \
        pk2(a0.COMP, a1.COMP),  pk2(a2.COMP, a3.COMP),                         \
        pk2(a4.COMP, a5.COMP),  pk2(a6.COMP, a7.COMP));                        \
    *(uint4*)(op + (E)*CH + 8) = make_uint4(                                   \
        pk2(a8.COMP, a9.COMP),  pk2(a10.COMP, a11.COMP),                       \
        pk2(a12.COMP, a13.COMP), pk2(a14.COMP, a15.COMP))

__global__ __launch_bounds__(256) void conv2_kernel(
    const unsigned short* __restrict__ y1,
    const float* __restrict__ w2, const float* __restrict__ b2, const float* __restrict__ a2p,
    unsigned short* __restrict__ xout)
{
    const int b    = blockIdx.x;
    const int wv   = threadIdx.x >> 6;
    const int lane = threadIdx.x & 63;
    const int f    = blockIdx.y*4 + wv;
    if (f >= NF) return;                      // wave-uniform; no barriers used
    const int gt0  = blockIdx.z*256 + lane*4;
    const int tc0  = (gt0 <= NT-4) ? gt0 : (NT-4);
    const float al2 = a2p[0];

    float4 a0  = make_float4(b2[0],b2[0],b2[0],b2[0]);
    float4 a1  = make_float4(b2[1],b2[1],b2[1],b2[1]);
    float4 a2  = make_float4(b2[2],b2[2],b2[2],b2[2]);
    float4 a3  = make_float4(b2[3],b2[3],b2[3],b2[3]);
    float4 a4  = make_float4(b2[4],b2[4],b2[4],b2[4]);
    float4 a5  = make_float4(b2[5],b2[5],b2[5],b2[5]);
    float4 a6  = make_float4(b2[6],b2[6],b2[6],b2[6]);
    float4 a7  = make_float4(b2[7],b2[7],b2[7],b2[7]);
    float4 a8  = make_float4(b2[8],b2[8],b2[8],b2[8]);
    float4 a9  = make_float4(b2[9],b2[9],b2[9],b2[9]);
    float4 a10 = make_float4(b2[10],b2[10],b2[10],b2[10]);
    float4 a11 = make_float4(b2[11],b2[11],b2[11],b2[11]);
    float4 a12 = make_float4(b2[12],b2[12],b2[12],b2[12]);
    float4 a13 = make_float4(b2[13],b2[13],b2[13],b2[13]);
    float4 a14 = make_float4(b2[14],b2[14],b2[14],b2[14]);
    float4 a15 = make_float4(b2[15],b2[15],b2[15],b2[15]);

    #pragma unroll
    for (int kk = 0; kk < 5; kk++) {
        const int fy = f + kk - 2;
        if (fy >= 0 && fy < NF) {             // wave-uniform (conv2 zero-pad)
            const unsigned short* yb = y1 + ((size_t)(b*NF + fy)*CH)*NT + tc0;
            #pragma unroll
            for (int ci = 0; ci < 16; ci++) {
                const uint2 u = *(const uint2*)(yb + ci*NT);
                const float4 v = ubf4(u);
                const float* wb = w2 + ci*5 + kk;
                P2ROW(wb, v);
            }
        }
    }

    if (gt0 < NT) {
        a0  = prelu4(a0,  al2); a1  = prelu4(a1,  al2);
        a2  = prelu4(a2,  al2); a3  = prelu4(a3,  al2);
        a4  = prelu4(a4,  al2); a5  = prelu4(a5,  al2);
        a6  = prelu4(a6,  al2); a7  = prelu4(a7,  al2);
        a8  = prelu4(a8,  al2); a9  = prelu4(a9,  al2);
        a10 = prelu4(a10, al2); a11 = prelu4(a11, al2);
        a12 = prelu4(a12, al2); a13 = prelu4(a13, al2);
        a14 = prelu4(a14, al2); a15 = prelu4(a15, al2);
        unsigned short* op = xout + ((size_t)(b*NF + f)*NT + gt0)*CH;
        STX(0, x); STX(1, y); STX(2, z); STX(3, w);
    }
}

// -------------------------------------------------------------------------
// GRU via MFMA (R8 structure, passed with absmax 3.9e-3).  Only change:
// x prefetch depth 1 -> 3 (HBM-miss ~900 cyc > one step's compute; the
// 1-deep pipeline stalled every step).
// -------------------------------------------------------------------------
__global__ __launch_bounds__(64) void gru_kernel(
    const unsigned short* __restrict__ xin,  // (NSEQ, NT, 16) bf16
    const float* __restrict__ h0,    // (NSEQ, 32)
    const float* __restrict__ w_ih,  // (96, 16)
    const float* __restrict__ w_hh,  // (96, 32)
    const float* __restrict__ b_ih, const float* __restrict__ b_hh,
    const float* __restrict__ fc_w, const float* __restrict__ fc_b,
    float* __restrict__ prob,        // (NSEQ, NT)
    float* __restrict__ hout)        // (NSEQ, 32)
{
    __shared__ unsigned short sv[16*72];     // [seq][72] bf16; stride 144B
    const int lane = threadIdx.x & 63;
    const int c    = lane & 15;
    const int quad = lane >> 4;
    const int base = blockIdx.x * 16;        // 481 blocks x 16 seq = 7696

    #define MKB(DST, G, CK)                                                    \
        { _Pragma("unroll") for (int j = 0; j < 8; j++) {                      \
            const int k = (CK)*32 + quad*8 + j;                                \
            const int g = (G);                                                 \
            float wv_;                                                         \
            if (g < 64)      wv_ = (k < 16) ? w_ih[g*16 + k]                   \
                                  : (k < 48) ? w_hh[g*32 + k - 16] : 0.f;      \
            else if (g < 96) wv_ = (k < 16) ? w_ih[g*16 + k] : 0.f;            \
            else             wv_ = (k >= 16 && k < 48)                         \
                                  ? w_hh[(g-32)*32 + k - 16] : 0.f;            \
            DST[j] = (short)f2bf(wv_); } }

    short8 B0a, B0b, B1a, B1b, B2a, B2b, B3a, B3b, B4a, B5a, B6a, B6b, B7a, B7b;
    MKB(B0a,       c, 0); MKB(B0b,       c, 1);   // r  units 0..15
    MKB(B1a,  16 + c, 0); MKB(B1b,  16 + c, 1);   // r  units 16..31
    MKB(B2a,  32 + c, 0); MKB(B2b,  32 + c, 1);   // z
    MKB(B3a,  48 + c, 0); MKB(B3b,  48 + c, 1);
    MKB(B4a,  64 + c, 0);                          // xn (chunk1 all-zero)
    MKB(B5a,  80 + c, 0);
    MKB(B6a,  96 + c, 0); MKB(B6b,  96 + c, 1);   // hn
    MKB(B7a, 112 + c, 0); MKB(B7b, 112 + c, 1);

    const float bi0 = b_ih[c]      + b_hh[c];
    const float bi1 = b_ih[16 + c] + b_hh[16 + c];
    const float bi2 = b_ih[32 + c] + b_hh[32 + c];
    const float bi3 = b_ih[48 + c] + b_hh[48 + c];
    const float bi4 = b_ih[64 + c];
    const float bi5 = b_ih[80 + c];
    const float bi6 = b_hh[64 + c];
    const float bi7 = b_hh[80 + c];
    const float fcw0 = fc_w[c], fcw1 = fc_w[16 + c];
    const float fb = fc_b[0];

    float hp00 = h0[(size_t)(base + quad*4 + 0)*HID + c];
    float hp01 = h0[(size_t)(base + quad*4 + 0)*HID + 16 + c];
    float hp10 = h0[(size_t)(base + quad*4 + 1)*HID + c];
    float hp11 = h0[(size_t)(base + quad*4 + 1)*HID + 16 + c];
    float hp20 = h0[(size_t)(base + quad*4 + 2)*HID + c];
    float hp21 = h0[(size_t)(base + quad*4 + 2)*HID + 16 + c];
    float hp30 = h0[(size_t)(base + quad*4 + 3)*HID + c];
    float hp31 = h0[(size_t)(base + quad*4 + 3)*HID + 16 + c];

    // ---- init LDS v-buffer ----
    *(uint2*)&sv[(lane >> 2)*72 + 48 + (lane & 3)*4] = make_uint2(0u, 0u);
    sv[(quad*4 + 0)*72 + 16 + c] = f2bf(hp00);  sv[(quad*4 + 0)*72 + 32 + c] = f2bf(hp01);
    sv[(quad*4 + 1)*72 + 16 + c] = f2bf(hp10);  sv[(quad*4 + 1)*72 + 32 + c] = f2bf(hp11);
    sv[(quad*4 + 2)*72 + 16 + c] = f2bf(hp20);  sv[(quad*4 + 2)*72 + 32 + c] = f2bf(hp21);
    sv[(quad*4 + 3)*72 + 16 + c] = f2bf(hp30);  sv[(quad*4 + 3)*72 + 32 + c] = f2bf(hp31);
    const unsigned short* xrow = xin + ((size_t)(base + (lane >> 2)))*NT*CH + (lane & 3)*4;
    {
        const uint2 x0v = *(const uint2*)(xrow);
        *(uint2*)&sv[(lane >> 2)*72 + (lane & 3)*4] = x0v;
    }
    uint2 nxA = *(const uint2*)(xrow + 1*CH);   // x(t=1)
    uint2 nxB = *(const uint2*)(xrow + 2*CH);   // x(t=2)
    __builtin_amdgcn_wave_barrier();

    #define GSTEP(R, HP0, HP1)                                                 \
        {                                                                      \
            const float rr0 = sig_(acc0[R]);                                   \
            const float rr1 = sig_(acc1[R]);                                   \
            const float zz0 = sig_(acc2[R]);                                   \
            const float zz1 = sig_(acc3[R]);                                   \
            const float aa0 = fmaf(rr0, acc6[R], acc4[R]);                     \
            const float aa1 = fmaf(rr1, acc7[R], acc5[R]);                     \
            const float nn0 = 2.f*sig_(2.f*aa0) - 1.f;                         \
            const float nn1 = 2.f*sig_(2.f*aa1) - 1.f;                         \
            HP0 = nn0 + zz0*(HP0 - nn0);                                       \
            HP1 = nn1 + zz1*(HP1 - nn1);                                       \
            sv[(quad*4 + (R))*72 + 16 + c] = f2bf(HP0);                        \
            sv[(quad*4 + (R))*72 + 32 + c] = f2bf(HP1);                        \
            float pa = fmaf(fcw1, HP1, fcw0*HP0);                              \
            pa += __shfl_xor(pa, 1);                                           \
            pa += __shfl_xor(pa, 2);                                           \
            pa += __shfl_xor(pa, 4);                                           \
            pa += __shfl_xor(pa, 8);                                           \
            if (c == 0)                                                        \
                prob[(size_t)(base + quad*4 + (R))*NT + t] = sig_(pa + fb);    \
        }

    for (int t = 0; t < NT; t++) {
        const short8 a0 = *(const short8*)&sv[c*72 + quad*8];        // k 0..31
        const short8 a1 = *(const short8*)&sv[c*72 + 32 + quad*8];   // k 32..63
        __builtin_amdgcn_wave_barrier();   // pin reads before this iter's writes

        // prefetch x(t+3): 3-deep pipeline covers ~900cyc HBM latency
        const int tn = (t + 3 < NT) ? t + 3 : NT - 1;
        const uint2 fx = *(const uint2*)(xrow + (size_t)tn*CH);

        f32x4 acc0 = {bi0, bi0, bi0, bi0};
        f32x4 acc1 = {bi1, bi1, bi1, bi1};
        f32x4 acc2 = {bi2, bi2, bi2, bi2};
        f32x4 acc3 = {bi3, bi3, bi3, bi3};
        f32x4 acc4 = {bi4, bi4, bi4, bi4};
        f32x4 acc5 = {bi5, bi5, bi5, bi5};
        f32x4 acc6 = {bi6, bi6, bi6, bi6};
        f32x4 acc7 = {bi7, bi7, bi7, bi7};

        acc0 = __builtin_amdgcn_mfma_f32_16x16x32_bf16(a0, B0a, acc0, 0, 0, 0);
        acc1 = __builtin_amdgcn_mfma_f32_16x16x32_bf16(a0, B1a, acc1, 0, 0, 0);
        acc2 = __builtin_amdgcn_mfma_f32_16x16x32_bf16(a0, B2a, acc2, 0, 0, 0);
        acc3 = __builtin_amdgcn_mfma_f32_16x16x32_bf16(a0, B3a, acc3, 0, 0, 0);
        acc4 = __builtin_amdgcn_mfma_f32_16x16x32_bf16(a0, B4a, acc4, 0, 0, 0);
        acc5 = __builtin_amdgcn_mfma_f32_16x16x32_bf16(a0, B5a, acc5, 0, 0, 0);
        acc6 = __builtin_amdgcn_mfma_f32_16x16x32_bf16(a0, B6a, acc6, 0, 0, 0);
        acc7 = __builtin_amdgcn_mfma_f32_16x16x32_bf16(a0, B7a, acc7, 0, 0, 0);
        acc0 = __builtin_amdgcn_mfma_f32_16x16x32_bf16(a1, B0b, acc0, 0, 0, 0);
        acc1 = __builtin_amdgcn_mfma_f32_16x16x32_bf16(a1, B1b, acc1, 0, 0, 0);
        acc2 = __builtin_amdgcn_mfma_f32_16x16x32_bf16(a1, B2b, acc2, 0, 0, 0);
        acc3 = __builtin_amdgcn_mfma_f32_16x16x32_bf16(a1, B3b, acc3, 0, 0, 0);
        acc6 = __builtin_amdgcn_mfma_f32_16x16x32_bf16(a1, B6b, acc6, 0, 0, 0);
        acc7 = __builtin_amdgcn_mfma_f32_16x16x32_bf16(a1, B7b, acc7, 0, 0, 0);

        GSTEP(0, hp00, hp01);
        GSTEP(1, hp10, hp11);
        GSTEP(2, hp20, hp21);
        GSTEP(3, hp30, hp31);

        // stage x(t+1) (held in nxA), rotate pipeline
        *(uint2*)&sv[(lane >> 2)*72 + (lane & 3)*4] = nxA;
        nxA = nxB; nxB = fx;
        __builtin_amdgcn_wave_barrier();
    }

    hout[(size_t)(base + quad*4 + 0)*HID + c]      = hp00;
    hout[(size_t)(base + quad*4 + 0)*HID + 16 + c] = hp01;
    hout[(size_t)(base + quad*4 + 1)*HID + c]      = hp10;
    hout[(size_t)(base + quad*4 + 1)*HID + 16 + c] = hp11;
    hout[(size_t)(base + quad*4 + 2)*HID + c]      = hp20;
    hout[(size_t)(base + quad*4 + 2)*HID + 16 + c] = hp21;
    hout[(size_t)(base + quad*4 + 3)*HID + c]      = hp30;
    hout[(size_t)(base + quad*4 + 3)*HID + 16 + c] = hp31;
}

// -------------------------------------------------------------------------
extern "C" void kernel_launch(void* const* d_in, const int* in_sizes, int n_in,
                              void* d_out, int out_size, void* d_ws, size_t ws_size,
                              hipStream_t stream)
{
    const float* feat = (const float*)d_in[0];
    const float* h0   = (const float*)d_in[1];
    const float* w1   = (const float*)d_in[2];
    const float* b1   = (const float*)d_in[3];
    const float* a1   = (const float*)d_in[4];
    const float* w2   = (const float*)d_in[5];
    const float* b2   = (const float*)d_in[6];
    const float* a2   = (const float*)d_in[7];
    const float* wih  = (const float*)d_in[8];
    const float* whh  = (const float*)d_in[9];
    const float* bih  = (const float*)d_in[10];
    const float* bhh  = (const float*)d_in[11];
    const float* fcw  = (const float*)d_in[12];
    const float* fcb  = (const float*)d_in[13];

    unsigned short* xbuf = (unsigned short*)d_ws;            // 123.1 MB bf16
    unsigned short* y1   = xbuf + (size_t)NSEQ*NT*CH;        // 123.1 MB bf16
    float* prob = (float*)d_out;                             // (B, F, T)
    float* hout = prob + (size_t)NSEQ*NT;                    // (1, NSEQ, 32)

    dim3 cgrid(NB, 121, 2);                                  // 4 f-waves/block
    conv1_kernel<<<cgrid, 256, 0, stream>>>(feat, w1, b1, a1, y1);
    conv2_kernel<<<cgrid, 256, 0, stream>>>(y1, w2, b2, a2, xbuf);
    gru_kernel<<<NSEQ/16, 64, 0, stream>>>(xbuf, h0, wih, whh, bih, bhh, fcw, fcb, prob, hout);
}

// Round 10
// 916.543 us; speedup vs baseline: 17.7929x; 1.3021x over previous
//
#include <hip/hip_runtime.h>

#define NF 481
#define NT 500
#define CH 16
#define HID 32
#define NB 16
#define NSEQ (NB*NF)   // 7696

typedef __attribute__((ext_vector_type(8))) short short8;
typedef __attribute__((ext_vector_type(4))) float f32x4;

__device__ __forceinline__ float sig_(float v) { return 1.0f / (1.0f + __expf(-v)); }

__device__ __forceinline__ unsigned short f2bf(float f) {
    unsigned u = __float_as_uint(f);
    u = (u + 0x7fffu + ((u >> 16) & 1u)) >> 16;   // RNE
    return (unsigned short)u;
}
__device__ __forceinline__ unsigned int pk2(float a, float b) {
    return (unsigned int)f2bf(a) | ((unsigned int)f2bf(b) << 16);
}
__device__ __forceinline__ float bf2f(short s) {
    return __uint_as_float(((unsigned)(unsigned short)s) << 16);
}
__device__ __forceinline__ float4 ubf4(uint2 u) {   // 4 bf16 -> 4 fp32
    float4 v;
    v.x = __uint_as_float(u.x << 16);
    v.y = __uint_as_float(u.x & 0xffff0000u);
    v.z = __uint_as_float(u.y << 16);
    v.w = __uint_as_float(u.y & 0xffff0000u);
    return v;
}
__device__ __forceinline__ float4 prelu4(float4 v, float a) {
    v.x = (v.x >= 0.f) ? v.x : a*v.x;
    v.y = (v.y >= 0.f) ? v.y : a*v.y;
    v.z = (v.z >= 0.f) ? v.z : a*v.z;
    v.w = (v.w >= 0.f) ? v.w : a*v.w;
    return v;
}

#define FMA4(Q, W, V)                     \
    Q.x = fmaf((W), (V).x, Q.x);          \
    Q.y = fmaf((W), (V).y, Q.y);          \
    Q.z = fmaf((W), (V).z, Q.z);          \
    Q.w = fmaf((W), (V).w, Q.w)

// -------------------------------------------------------------------------
// Pass 1: conv1(4->16,k9,p4) + PReLU -> y1 (b, f, ch, t) bf16.
// (unchanged from R9 — out of top-5)
// -------------------------------------------------------------------------
#define P1TAP(D, K1)                                                           \
    {                                                                          \
        const int gf = f + (K1) - 4;                                           \
        if (gf >= 0 && gf < NF) {                                              \
            const float4 v = *(const float4*)(feat +                           \
                ((size_t)(b*4 + (D))*NF + gf)*NT + tc0);                       \
            FMA4(q0,  w1[ 0*36 + (D)*9 + (K1)], v);                            \
            FMA4(q1,  w1[ 1*36 + (D)*9 + (K1)], v);                            \
            FMA4(q2,  w1[ 2*36 + (D)*9 + (K1)], v);                            \
            FMA4(q3,  w1[ 3*36 + (D)*9 + (K1)], v);                            \
            FMA4(q4,  w1[ 4*36 + (D)*9 + (K1)], v);                            \
            FMA4(q5,  w1[ 5*36 + (D)*9 + (K1)], v);                            \
            FMA4(q6,  w1[ 6*36 + (D)*9 + (K1)], v);                            \
            FMA4(q7,  w1[ 7*36 + (D)*9 + (K1)], v);                            \
            FMA4(q8,  w1[ 8*36 + (D)*9 + (K1)], v);                            \
            FMA4(q9,  w1[ 9*36 + (D)*9 + (K1)], v);                            \
            FMA4(q10, w1[10*36 + (D)*9 + (K1)], v);                            \
            FMA4(q11, w1[11*36 + (D)*9 + (K1)], v);                            \
            FMA4(q12, w1[12*36 + (D)*9 + (K1)], v);                            \
            FMA4(q13, w1[13*36 + (D)*9 + (K1)], v);                            \
            FMA4(q14, w1[14*36 + (D)*9 + (K1)], v);                            \
            FMA4(q15, w1[15*36 + (D)*9 + (K1)], v);                            \
        }                                                                      \
    }

__global__ __launch_bounds__(256) void conv1_kernel(
    const float* __restrict__ feat,
    const float* __restrict__ w1, const float* __restrict__ b1, const float* __restrict__ a1p,
    unsigned short* __restrict__ y1)
{
    const int b    = blockIdx.x;
    const int wv   = threadIdx.x >> 6;
    const int lane = threadIdx.x & 63;
    const int f    = blockIdx.y*4 + wv;
    if (f >= NF) return;
    const int gt0  = blockIdx.z*256 + lane*4;
    const int tc0  = (gt0 <= NT-4) ? gt0 : (NT-4);
    const float al1 = a1p[0];

    float4 q0  = make_float4(b1[0],b1[0],b1[0],b1[0]);
    float4 q1  = make_float4(b1[1],b1[1],b1[1],b1[1]);
    float4 q2  = make_float4(b1[2],b1[2],b1[2],b1[2]);
    float4 q3  = make_float4(b1[3],b1[3],b1[3],b1[3]);
    float4 q4  = make_float4(b1[4],b1[4],b1[4],b1[4]);
    float4 q5  = make_float4(b1[5],b1[5],b1[5],b1[5]);
    float4 q6  = make_float4(b1[6],b1[6],b1[6],b1[6]);
    float4 q7  = make_float4(b1[7],b1[7],b1[7],b1[7]);
    float4 q8  = make_float4(b1[8],b1[8],b1[8],b1[8]);
    float4 q9  = make_float4(b1[9],b1[9],b1[9],b1[9]);
    float4 q10 = make_float4(b1[10],b1[10],b1[10],b1[10]);
    float4 q11 = make_float4(b1[11],b1[11],b1[11],b1[11]);
    float4 q12 = make_float4(b1[12],b1[12],b1[12],b1[12]);
    float4 q13 = make_float4(b1[13],b1[13],b1[13],b1[13]);
    float4 q14 = make_float4(b1[14],b1[14],b1[14],b1[14]);
    float4 q15 = make_float4(b1[15],b1[15],b1[15],b1[15]);

    #pragma unroll
    for (int d = 0; d < 4; d++) {
        P1TAP(d, 0); P1TAP(d, 1); P1TAP(d, 2); P1TAP(d, 3); P1TAP(d, 4);
        P1TAP(d, 5); P1TAP(d, 6); P1TAP(d, 7); P1TAP(d, 8);
    }

    if (gt0 < NT) {
        unsigned short* yb = y1 + ((size_t)(b*NF + f)*CH)*NT + gt0;
        q0  = prelu4(q0,  al1); q1  = prelu4(q1,  al1);
        q2  = prelu4(q2,  al1); q3  = prelu4(q3,  al1);
        q4  = prelu4(q4,  al1); q5  = prelu4(q5,  al1);
        q6  = prelu4(q6,  al1); q7  = prelu4(q7,  al1);
        q8  = prelu4(q8,  al1); q9  = prelu4(q9,  al1);
        q10 = prelu4(q10, al1); q11 = prelu4(q11, al1);
        q12 = prelu4(q12, al1); q13 = prelu4(q13, al1);
        q14 = prelu4(q14, al1); q15 = prelu4(q15, al1);
        *(uint2*)(yb +  0*NT) = make_uint2(pk2(q0.x, q0.y),  pk2(q0.z, q0.w));
        *(uint2*)(yb +  1*NT) = make_uint2(pk2(q1.x, q1.y),  pk2(q1.z, q1.w));
        *(uint2*)(yb +  2*NT) = make_uint2(pk2(q2.x, q2.y),  pk2(q2.z, q2.w));
        *(uint2*)(yb +  3*NT) = make_uint2(pk2(q3.x, q3.y),  pk2(q3.z, q3.w));
        *(uint2*)(yb +  4*NT) = make_uint2(pk2(q4.x, q4.y),  pk2(q4.z, q4.w));
        *(uint2*)(yb +  5*NT) = make_uint2(pk2(q5.x, q5.y),  pk2(q5.z, q5.w));
        *(uint2*)(yb +  6*NT) = make_uint2(pk2(q6.x, q6.y),  pk2(q6.z, q6.w));
        *(uint2*)(yb +  7*NT) = make_uint2(pk2(q7.x, q7.y),  pk2(q7.z, q7.w));
        *(uint2*)(yb +  8*NT) = make_uint2(pk2(q8.x, q8.y),  pk2(q8.z, q8.w));
        *(uint2*)(yb +  9*NT) = make_uint2(pk2(q9.x, q9.y),  pk2(q9.z, q9.w));
        *(uint2*)(yb + 10*NT) = make_uint2(pk2(q10.x,q10.y), pk2(q10.z,q10.w));
        *(uint2*)(yb + 11*NT) = make_uint2(pk2(q11.x,q11.y), pk2(q11.z,q11.w));
        *(uint2*)(yb + 12*NT) = make_uint2(pk2(q12.x,q12.y), pk2(q12.z,q12.w));
        *(uint2*)(yb + 13*NT) = make_uint2(pk2(q13.x,q13.y), pk2(q13.z,q13.w));
        *(uint2*)(yb + 14*NT) = make_uint2(pk2(q14.x,q14.y), pk2(q14.z,q14.w));
        *(uint2*)(yb + 15*NT) = make_uint2(pk2(q15.x,q15.y), pk2(q15.z,q15.w));
    }
}

// -------------------------------------------------------------------------
// Pass 2: conv2(16->16,k5,p2) + PReLU -> x (n, t, 16) bf16.
// (unchanged from R9)
// -------------------------------------------------------------------------
#define P2ROW(WB, V)                                                           \
    FMA4(a0,  (WB)[0],    V); FMA4(a1,  (WB)[80],   V);                        \
    FMA4(a2,  (WB)[160],  V); FMA4(a3,  (WB)[240],  V);                        \
    FMA4(a4,  (WB)[320],  V); FMA4(a5,  (WB)[400],  V);                        \
    FMA4(a6,  (WB)[480],  V); FMA4(a7,  (WB)[560],  V);                        \
    FMA4(a8,  (WB)[640],  V); FMA4(a9,  (WB)[720],  V);                        \
    FMA4(a10, (WB)[800],  V); FMA4(a11, (WB)[880],  V);                        \
    FMA4(a12, (WB)[960],  V); FMA4(a13, (WB)[1040], V);                        \
    FMA4(a14, (WB)[1120], V); FMA4(a15, (WB)[1200], V)

#define STX(E, COMP)                                                           \
    *(uint4*)(op + (E)*CH) = make_uint4(                                       \
        pk2(a0.COMP, a1.COMP),  pk2(a2.COMP, a3.COMP),                         \
        pk2(a4.COMP, a5.COMP),  pk2(a6.COMP, a7.COMP));                        \
    *(uint4*)(op + (E)*CH + 8) = make_uint4(                                   \
        pk2(a8.COMP, a9.COMP),  pk2(a10.COMP, a11.COMP),                       \
        pk2(a12.COMP, a13.COMP), pk2(a14.COMP, a15.COMP))

__global__ __launch_bounds__(256) void conv2_kernel(
    const unsigned short* __restrict__ y1,
    const float* __restrict__ w2, const float* __restrict__ b2, const float* __restrict__ a2p,
    unsigned short* __restrict__ xout)
{
    const int b    = blockIdx.x;
    const int wv   = threadIdx.x >> 6;
    const int lane = threadIdx.x & 63;
    const int f    = blockIdx.y*4 + wv;
    if (f >= NF) return;
    const int gt0  = blockIdx.z*256 + lane*4;
    const int tc0  = (gt0 <= NT-4) ? gt0 : (NT-4);
    const float al2 = a2p[0];

    float4 a0  = make_float4(b2[0],b2[0],b2[0],b2[0]);
    float4 a1  = make_float4(b2[1],b2[1],b2[1],b2[1]);
    float4 a2  = make_float4(b2[2],b2[2],b2[2],b2[2]);
    float4 a3  = make_float4(b2[3],b2[3],b2[3],b2[3]);
    float4 a4  = make_float4(b2[4],b2[4],b2[4],b2[4]);
    float4 a5  = make_float4(b2[5],b2[5],b2[5],b2[5]);
    float4 a6  = make_float4(b2[6],b2[6],b2[6],b2[6]);
    float4 a7  = make_float4(b2[7],b2[7],b2[7],b2[7]);
    float4 a8  = make_float4(b2[8],b2[8],b2[8],b2[8]);
    float4 a9  = make_float4(b2[9],b2[9],b2[9],b2[9]);
    float4 a10 = make_float4(b2[10],b2[10],b2[10],b2[10]);
    float4 a11 = make_float4(b2[11],b2[11],b2[11],b2[11]);
    float4 a12 = make_float4(b2[12],b2[12],b2[12],b2[12]);
    float4 a13 = make_float4(b2[13],b2[13],b2[13],b2[13]);
    float4 a14 = make_float4(b2[14],b2[14],b2[14],b2[14]);
    float4 a15 = make_float4(b2[15],b2[15],b2[15],b2[15]);

    #pragma unroll
    for (int kk = 0; kk < 5; kk++) {
        const int fy = f + kk - 2;
        if (fy >= 0 && fy < NF) {
            const unsigned short* yb = y1 + ((size_t)(b*NF + fy)*CH)*NT + tc0;
            #pragma unroll
            for (int ci = 0; ci < 16; ci++) {
                const uint2 u = *(const uint2*)(yb + ci*NT);
                const float4 v = ubf4(u);
                const float* wb = w2 + ci*5 + kk;
                P2ROW(wb, v);
            }
        }
    }

    if (gt0 < NT) {
        a0  = prelu4(a0,  al2); a1  = prelu4(a1,  al2);
        a2  = prelu4(a2,  al2); a3  = prelu4(a3,  al2);
        a4  = prelu4(a4,  al2); a5  = prelu4(a5,  al2);
        a6  = prelu4(a6,  al2); a7  = prelu4(a7,  al2);
        a8  = prelu4(a8,  al2); a9  = prelu4(a9,  al2);
        a10 = prelu4(a10, al2); a11 = prelu4(a11, al2);
        a12 = prelu4(a12, al2); a13 = prelu4(a13, al2);
        a14 = prelu4(a14, al2); a15 = prelu4(a15, al2);
        unsigned short* op = xout + ((size_t)(b*NF + f)*NT + gt0)*CH;
        STX(0, x); STX(1, y); STX(2, z); STX(3, w);
    }
}

// -------------------------------------------------------------------------
// GRU via MFMA (R8/R9 core).  R9 lesson: 5.5% occupancy -> wall time is the
// single wave's critical path (~4200 cyc/step); the 16 serialized
// ds_bpermute+lgkmcnt(0) of the in-loop FC were the bulk.  This round the
// FC for prob[t-1] is computed from the A-fragments (which hold h_t):
// one extra 16B LDS read + 16 VALU + ONLY 2 shuffles (xor16, xor32),
// with the 14 MFMAs issued between them to hide bpermute latency.
// GSTEP loses all shuffles/stores.  prob[NT-1] handled in an epilogue.
// -------------------------------------------------------------------------
__global__ __launch_bounds__(64) void gru_kernel(
    const unsigned short* __restrict__ xin,  // (NSEQ, NT, 16) bf16
    const float* __restrict__ h0,    // (NSEQ, 32)
    const float* __restrict__ w_ih,  // (96, 16)
    const float* __restrict__ w_hh,  // (96, 32)
    const float* __restrict__ b_ih, const float* __restrict__ b_hh,
    const float* __restrict__ fc_w, const float* __restrict__ fc_b,
    float* __restrict__ prob,        // (NSEQ, NT)
    float* __restrict__ hout)        // (NSEQ, 32)
{
    __shared__ unsigned short sv[16*72];     // [seq][x16|h32|pad16] bf16
    const int lane = threadIdx.x & 63;
    const int c    = lane & 15;
    const int quad = lane >> 4;
    const int base = blockIdx.x * 16;        // 481 blocks x 16 seq

    #define MKB(DST, G, CK)                                                    \
        { _Pragma("unroll") for (int j = 0; j < 8; j++) {                      \
            const int k = (CK)*32 + quad*8 + j;                                \
            const int g = (G);                                                 \
            float wv_;                                                         \
            if (g < 64)      wv_ = (k < 16) ? w_ih[g*16 + k]                   \
                                  : (k < 48) ? w_hh[g*32 + k - 16] : 0.f;      \
            else if (g < 96) wv_ = (k < 16) ? w_ih[g*16 + k] : 0.f;            \
            else             wv_ = (k >= 16 && k < 48)                         \
                                  ? w_hh[(g-32)*32 + k - 16] : 0.f;            \
            DST[j] = (short)f2bf(wv_); } }

    short8 B0a, B0b, B1a, B1b, B2a, B2b, B3a, B3b, B4a, B5a, B6a, B6b, B7a, B7b;
    MKB(B0a,       c, 0); MKB(B0b,       c, 1);   // r  units 0..15
    MKB(B1a,  16 + c, 0); MKB(B1b,  16 + c, 1);   // r  units 16..31
    MKB(B2a,  32 + c, 0); MKB(B2b,  32 + c, 1);   // z
    MKB(B3a,  48 + c, 0); MKB(B3b,  48 + c, 1);
    MKB(B4a,  64 + c, 0);                          // xn (chunk1 all-zero)
    MKB(B5a,  80 + c, 0);
    MKB(B6a,  96 + c, 0); MKB(B6b,  96 + c, 1);   // hn
    MKB(B7a, 112 + c, 0); MKB(B7b, 112 + c, 1);

    const float bi0 = b_ih[c]      + b_hh[c];
    const float bi1 = b_ih[16 + c] + b_hh[16 + c];
    const float bi2 = b_ih[32 + c] + b_hh[32 + c];
    const float bi3 = b_ih[48 + c] + b_hh[48 + c];
    const float bi4 = b_ih[64 + c];
    const float bi5 = b_ih[80 + c];
    const float bi6 = b_hh[64 + c];
    const float bi7 = b_hh[80 + c];
    const float fb = fc_b[0];

    // per-lane FC slice: this lane reads h units u0..u0+7 of seq c
    const int u0 = (quad == 0) ? 16 : (quad == 1) ? 24 : (quad == 2) ? 0 : 8;
    float fsl0 = fc_w[u0+0], fsl1 = fc_w[u0+1], fsl2 = fc_w[u0+2], fsl3 = fc_w[u0+3];
    float fsl4 = fc_w[u0+4], fsl5 = fc_w[u0+5], fsl6 = fc_w[u0+6], fsl7 = fc_w[u0+7];

    float hp00 = h0[(size_t)(base + quad*4 + 0)*HID + c];
    float hp01 = h0[(size_t)(base + quad*4 + 0)*HID + 16 + c];
    float hp10 = h0[(size_t)(base + quad*4 + 1)*HID + c];
    float hp11 = h0[(size_t)(base + quad*4 + 1)*HID + 16 + c];
    float hp20 = h0[(size_t)(base + quad*4 + 2)*HID + c];
    float hp21 = h0[(size_t)(base + quad*4 + 2)*HID + 16 + c];
    float hp30 = h0[(size_t)(base + quad*4 + 3)*HID + c];
    float hp31 = h0[(size_t)(base + quad*4 + 3)*HID + 16 + c];

    // ---- init LDS v-buffer ----
    *(uint2*)&sv[(lane >> 2)*72 + 48 + (lane & 3)*4] = make_uint2(0u, 0u);
    sv[(quad*4 + 0)*72 + 16 + c] = f2bf(hp00);  sv[(quad*4 + 0)*72 + 32 + c] = f2bf(hp01);
    sv[(quad*4 + 1)*72 + 16 + c] = f2bf(hp10);  sv[(quad*4 + 1)*72 + 32 + c] = f2bf(hp11);
    sv[(quad*4 + 2)*72 + 16 + c] = f2bf(hp20);  sv[(quad*4 + 2)*72 + 32 + c] = f2bf(hp21);
    sv[(quad*4 + 3)*72 + 16 + c] = f2bf(hp30);  sv[(quad*4 + 3)*72 + 32 + c] = f2bf(hp31);
    const unsigned short* xrow = xin + ((size_t)(base + (lane >> 2)))*NT*CH + (lane & 3)*4;
    {
        const uint2 x0v = *(const uint2*)(xrow);
        *(uint2*)&sv[(lane >> 2)*72 + (lane & 3)*4] = x0v;
    }
    uint2 nxA = *(const uint2*)(xrow + 1*CH);   // x(t=1)
    uint2 nxB = *(const uint2*)(xrow + 2*CH);   // x(t=2)
    __builtin_amdgcn_wave_barrier();

    #define GSTEP(R, HP0, HP1)                                                 \
        {                                                                      \
            const float rr0 = sig_(acc0[R]);                                   \
            const float rr1 = sig_(acc1[R]);                                   \
            const float zz0 = sig_(acc2[R]);                                   \
            const float zz1 = sig_(acc3[R]);                                   \
            const float aa0 = fmaf(rr0, acc6[R], acc4[R]);                     \
            const float aa1 = fmaf(rr1, acc7[R], acc5[R]);                     \
            const float nn0 = 2.f*sig_(2.f*aa0) - 1.f;                         \
            const float nn1 = 2.f*sig_(2.f*aa1) - 1.f;                         \
            HP0 = nn0 + zz0*(HP0 - nn0);                                       \
            HP1 = nn1 + zz1*(HP1 - nn1);                                       \
            sv[(quad*4 + (R))*72 + 16 + c] = f2bf(HP0);                        \
            sv[(quad*4 + (R))*72 + 32 + c] = f2bf(HP1);                        \
        }

    for (int t = 0; t < NT; t++) {
        const short8 a0  = *(const short8*)&sv[c*72 + quad*8];        // k 0..31
        const short8 a1  = *(const short8*)&sv[c*72 + 32 + quad*8];   // k 32..63
        const short8 hs8 = *(const short8*)&sv[c*72 + 16 + u0];       // h slice
        __builtin_amdgcn_wave_barrier();   // pin reads before this iter's writes

        // FC partial for prob[t-1] (h_t is in sv): 8-term dot
        float pa;
        pa = bf2f(hs8[0])*fsl0;
        pa = fmaf(bf2f(hs8[1]), fsl1, pa);
        pa = fmaf(bf2f(hs8[2]), fsl2, pa);
        pa = fmaf(bf2f(hs8[3]), fsl3, pa);
        pa = fmaf(bf2f(hs8[4]), fsl4, pa);
        pa = fmaf(bf2f(hs8[5]), fsl5, pa);
        pa = fmaf(bf2f(hs8[6]), fsl6, pa);
        pa = fmaf(bf2f(hs8[7]), fsl7, pa);
        pa += __shfl_xor(pa, 16);          // combine quad pairs (latency hidden by MFMAs)

        // prefetch x(t+3)
        const int tn = (t + 3 < NT) ? t + 3 : NT - 1;
        const uint2 fx = *(const uint2*)(xrow + (size_t)tn*CH);

        f32x4 acc0 = {bi0, bi0, bi0, bi0};
        f32x4 acc1 = {bi1, bi1, bi1, bi1};
        f32x4 acc2 = {bi2, bi2, bi2, bi2};
        f32x4 acc3 = {bi3, bi3, bi3, bi3};
        f32x4 acc4 = {bi4, bi4, bi4, bi4};
        f32x4 acc5 = {bi5, bi5, bi5, bi5};
        f32x4 acc6 = {bi6, bi6, bi6, bi6};
        f32x4 acc7 = {bi7, bi7, bi7, bi7};

        acc0 = __builtin_amdgcn_mfma_f32_16x16x32_bf16(a0, B0a, acc0, 0, 0, 0);
        acc1 = __builtin_amdgcn_mfma_f32_16x16x32_bf16(a0, B1a, acc1, 0, 0, 0);
        acc2 = __builtin_amdgcn_mfma_f32_16x16x32_bf16(a0, B2a, acc2, 0, 0, 0);
        acc3 = __builtin_amdgcn_mfma_f32_16x16x32_bf16(a0, B3a, acc3, 0, 0, 0);
        acc4 = __builtin_amdgcn_mfma_f32_16x16x32_bf16(a0, B4a, acc4, 0, 0, 0);
        acc5 = __builtin_amdgcn_mfma_f32_16x16x32_bf16(a0, B5a, acc5, 0, 0, 0);
        acc6 = __builtin_amdgcn_mfma_f32_16x16x32_bf16(a0, B6a, acc6, 0, 0, 0);
        acc7 = __builtin_amdgcn_mfma_f32_16x16x32_bf16(a0, B7a, acc7, 0, 0, 0);
        acc0 = __builtin_amdgcn_mfma_f32_16x16x32_bf16(a1, B0b, acc0, 0, 0, 0);
        acc1 = __builtin_amdgcn_mfma_f32_16x16x32_bf16(a1, B1b, acc1, 0, 0, 0);
        acc2 = __builtin_amdgcn_mfma_f32_16x16x32_bf16(a1, B2b, acc2, 0, 0, 0);
        acc3 = __builtin_amdgcn_mfma_f32_16x16x32_bf16(a1, B3b, acc3, 0, 0, 0);
        acc6 = __builtin_amdgcn_mfma_f32_16x16x32_bf16(a1, B6b, acc6, 0, 0, 0);
        acc7 = __builtin_amdgcn_mfma_f32_16x16x32_bf16(a1, B7b, acc7, 0, 0, 0);

        // finish the FC reduction + store (prob for step t-1)
        pa += __shfl_xor(pa, 32);
        if (t > 0 && lane < 16)
            prob[(size_t)(base + c)*NT + (t - 1)] = sig_(pa + fb);

        GSTEP(0, hp00, hp01);
        GSTEP(1, hp10, hp11);
        GSTEP(2, hp20, hp21);
        GSTEP(3, hp30, hp31);

        // stage x(t+1), rotate prefetch pipeline
        *(uint2*)&sv[(lane >> 2)*72 + (lane & 3)*4] = nxA;
        nxA = nxB; nxB = fx;
        __builtin_amdgcn_wave_barrier();
    }

    // prob for the final step (h_NT is in sv)
    {
        const short8 hs8 = *(const short8*)&sv[c*72 + 16 + u0];
        float pa;
        pa = bf2f(hs8[0])*fsl0;
        pa = fmaf(bf2f(hs8[1]), fsl1, pa);
        pa = fmaf(bf2f(hs8[2]), fsl2, pa);
        pa = fmaf(bf2f(hs8[3]), fsl3, pa);
        pa = fmaf(bf2f(hs8[4]), fsl4, pa);
        pa = fmaf(bf2f(hs8[5]), fsl5, pa);
        pa = fmaf(bf2f(hs8[6]), fsl6, pa);
        pa = fmaf(bf2f(hs8[7]), fsl7, pa);
        pa += __shfl_xor(pa, 16);
        pa += __shfl_xor(pa, 32);
        if (lane < 16)
            prob[(size_t)(base + c)*NT + (NT - 1)] = sig_(pa + fb);
    }

    hout[(size_t)(base + quad*4 + 0)*HID + c]      = hp00;
    hout[(size_t)(base + quad*4 + 0)*HID + 16 + c] = hp01;
    hout[(size_t)(base + quad*4 + 1)*HID + c]      = hp10;
    hout[(size_t)(base + quad*4 + 1)*HID + 16 + c] = hp11;
    hout[(size_t)(base + quad*4 + 2)*HID + c]      = hp20;
    hout[(size_t)(base + quad*4 + 2)*HID + 16 + c] = hp21;
    hout[(size_t)(base + quad*4 + 3)*HID + c]      = hp30;
    hout[(size_t)(base + quad*4 + 3)*HID + 16 + c] = hp31;
}

// -------------------------------------------------------------------------
extern "C" void kernel_launch(void* const* d_in, const int* in_sizes, int n_in,
                              void* d_out, int out_size, void* d_ws, size_t ws_size,
                              hipStream_t stream)
{
    const float* feat = (const float*)d_in[0];
    const float* h0   = (const float*)d_in[1];
    const float* w1   = (const float*)d_in[2];
    const float* b1   = (const float*)d_in[3];
    const float* a1   = (const float*)d_in[4];
    const float* w2   = (const float*)d_in[5];
    const float* b2   = (const float*)d_in[6];
    const float* a2   = (const float*)d_in[7];
    const float* wih  = (const float*)d_in[8];
    const float* whh  = (const float*)d_in[9];
    const float* bih  = (const float*)d_in[10];
    const float* bhh  = (const float*)d_in[11];
    const float* fcw  = (const float*)d_in[12];
    const float* fcb  = (const float*)d_in[13];

    unsigned short* xbuf = (unsigned short*)d_ws;            // 123.1 MB bf16
    unsigned short* y1   = xbuf + (size_t)NSEQ*NT*CH;        // 123.1 MB bf16
    float* prob = (float*)d_out;                             // (B, F, T)
    float* hout = prob + (size_t)NSEQ*NT;                    // (1, NSEQ, 32)

    dim3 cgrid(NB, 121, 2);                                  // 4 f-waves/block
    conv1_kernel<<<cgrid, 256, 0, stream>>>(feat, w1, b1, a1, y1);
    conv2_kernel<<<cgrid, 256, 0, stream>>>(y1, w2, b2, a2, xbuf);
    gru_kernel<<<NSEQ/16, 64, 0, stream>>>(xbuf, h0, wih, whh, bih, bhh, fcw, fcb, prob, hout);
}